// Round 9
// baseline (633.542 us; speedup 1.0000x reference)
//
#include <hip/hip_runtime.h>
#include <cmath>

#define EPS_BN 1e-5f
#define EPS_SM 1e-16f

typedef _Float16 f16x8 __attribute__((ext_vector_type(8)));
typedef _Float16 f16x4 __attribute__((ext_vector_type(4)));
typedef _Float16 h2 __attribute__((ext_vector_type(2)));
typedef float f32x4 __attribute__((ext_vector_type(4)));
union F4 { float4 v; float a[4]; };

// ============================ utility: zero fill ============================
__global__ void zero_kernel(int* __restrict__ p, int n) {
    int i = blockIdx.x * 256 + threadIdx.x;
    if (i < n) p[i] = 0;
}

// ============================ CSR build ============================
__global__ void hist_kernel(const int* __restrict__ edst, int* __restrict__ deg, int E) {
    int e = blockIdx.x * 256 + threadIdx.x;
    if (e < E) atomicAdd(&deg[edst[e]], 1);
}

__global__ void scan1_kernel(const int* __restrict__ deg, int* __restrict__ row_ptr,
                             int* __restrict__ bsum, int N) {
    __shared__ int s[256];
    int t = threadIdx.x;
    int i = blockIdx.x * 256 + t;
    int v = (i < N) ? deg[i] : 0;
    s[t] = v; __syncthreads();
    for (int off = 1; off < 256; off <<= 1) {
        int x = (t >= off) ? s[t - off] : 0;
        __syncthreads();
        s[t] += x;
        __syncthreads();
    }
    if (i < N) row_ptr[i] = s[t] - v;   // exclusive partial
    if (t == 255) bsum[blockIdx.x] = s[t];
}

__global__ void scan2_kernel(int* __restrict__ bsum, int nb) {
    __shared__ int s[1024];
    int t = threadIdx.x;
    int v = (t < nb) ? bsum[t] : 0;
    s[t] = v; __syncthreads();
    for (int off = 1; off < 1024; off <<= 1) {
        int x = (t >= off) ? s[t - off] : 0;
        __syncthreads();
        s[t] += x;
        __syncthreads();
    }
    if (t < nb) bsum[t] = s[t] - v;     // exclusive
}

__global__ void scan3_kernel(int* __restrict__ row_ptr, int* __restrict__ cursor,
                             const int* __restrict__ bsum, int N, int E) {
    int i = blockIdx.x * 256 + threadIdx.x;
    if (i < N) {
        int v = row_ptr[i] + bsum[blockIdx.x];
        row_ptr[i] = v;
        cursor[i] = v;
    } else if (i == N) {
        row_ptr[N] = E;
    }
}

// Qm3[l][f*4+hh] = sum_c conv_we[l][f][hh*64+c] * att_edge[l][hh][c]   (BN-independent)
__global__ void qm3_kernel(const float* __restrict__ convwe, const float* __restrict__ atte,
                           float* __restrict__ Qm3) {
    int t = threadIdx.x;
    if (t >= 96) return;
    int l = t >> 5, f = (t >> 2) & 7, hh = t & 3;
    const float* we = convwe + (size_t)l * 8 * 256;
    const float* av = atte + (size_t)l * 256;
    float acc = 0.f;
    for (int c = 0; c < 64; c++) acc += we[f * 256 + hh * 64 + c] * av[hh * 64 + c];
    Qm3[t] = acc;
}

// scatter edges to CSR order: src_csr[p] = src, ae_csr[l][p][4] = f16(edge_attr@Qm3[l])
__global__ void scatter_kernel(const int* __restrict__ esrc, const int* __restrict__ edst,
                               const float* __restrict__ edge_attr, const float* __restrict__ Qm3,
                               int* __restrict__ cursor, int* __restrict__ src_csr,
                               _Float16* __restrict__ ae_csr, int E) {
    __shared__ float q[96];
    int t = threadIdx.x;
    if (t < 96) q[t] = Qm3[t];
    __syncthreads();
    int e = blockIdx.x * 256 + t;
    if (e >= E) return;
    int src = esrc[e];
    int p = atomicAdd(&cursor[edst[e]], 1);
    src_csr[p] = src;
    F4 ea0, ea1;
    ea0.v = ((const float4*)edge_attr)[(size_t)e * 2];
    ea1.v = ((const float4*)edge_attr)[(size_t)e * 2 + 1];
#pragma unroll
    for (int l = 0; l < 3; l++) {
        const float* ql = q + l * 32;
        f16x4 r;
#pragma unroll
        for (int hh = 0; hh < 4; hh++) {
            float acc = ea0.a[0] * ql[0 * 4 + hh] + ea0.a[1] * ql[1 * 4 + hh]
                      + ea0.a[2] * ql[2 * 4 + hh] + ea0.a[3] * ql[3 * 4 + hh]
                      + ea1.a[0] * ql[4 * 4 + hh] + ea1.a[1] * ql[5 * 4 + hh]
                      + ea1.a[2] * ql[6 * 4 + hh] + ea1.a[3] * ql[7 * 4 + hh];
            r[hh] = (_Float16)acc;
        }
        *(f16x4*)(ae_csr + ((size_t)l * E + p) * 4) = r;
    }
}

// graph ranges by binary search (batch is sorted)
__global__ void gptr_kernel(const int* __restrict__ batch, int* __restrict__ gptr, int N, int G) {
    int g = blockIdx.x * 256 + threadIdx.x;
    if (g > G) return;
    int lo = 0, hi = N;
    while (lo < hi) { int mid = (lo + hi) >> 1; if (batch[mid] < g) lo = mid + 1; else hi = mid; }
    gptr[g] = lo;
}

// ============================ input projection (h16 + BN partial atomics) ============================
__global__ void proj_kernel(const float* __restrict__ x, const float* __restrict__ lin_w,
                            const float* __restrict__ lin_b,
                            _Float16* __restrict__ h16, float* __restrict__ bnp, int N) {
    __shared__ float Xs[64 * 32];
    __shared__ float ls[256], lq[256];
    int t = threadIdx.x;
    int col = t & 63, sub = t >> 6;
    float w[32];
#pragma unroll
    for (int k = 0; k < 32; k++) w[k] = lin_w[k * 64 + col];
    float b = lin_b[col];
    int r0 = blockIdx.x * 64;
    const float4* xg = (const float4*)(x + (size_t)r0 * 32);
    float4* Xs4 = (float4*)Xs;
    size_t totf4 = (size_t)N * 8;
#pragma unroll
    for (int i = 0; i < 2; i++) {
        int idx = t + i * 256;
        size_t gidx = (size_t)r0 * 8 + idx;
        Xs4[idx] = (gidx < totf4) ? xg[idx] : make_float4(0.f, 0.f, 0.f, 0.f);
    }
    __syncthreads();
    float ps = 0.f, pq = 0.f;
    for (int rr = sub; rr < 64; rr += 4) {
        int r = r0 + rr;
        if (r >= N) break;
        float acc = b;
        const float4* a4p = (const float4*)(Xs + rr * 32);
#pragma unroll
        for (int kk = 0; kk < 8; kk++) {
            float4 a4 = a4p[kk];
            acc += a4.x * w[kk * 4] + a4.y * w[kk * 4 + 1] + a4.z * w[kk * 4 + 2] + a4.w * w[kk * 4 + 3];
        }
        float hv = fmaxf(acc, 0.f);
        h16[(size_t)r * 64 + col] = (_Float16)hv;
        ps += hv; pq += hv * hv;
    }
    ls[t] = ps; lq[t] = pq;
    __syncthreads();
    if (t < 64) {
        int slot = blockIdx.x & 255;
        atomicAdd(&bnp[(size_t)t * 256 + slot], ls[t] + ls[t + 64] + ls[t + 128] + ls[t + 192]);
        atomicAdd(&bnp[(size_t)(64 + t) * 256 + slot], lq[t] + lq[t + 64] + lq[t + 128] + lq[t + 192]);
    }
}

// ============================ fold (parallel, inline 256-slot reduction) ============================
// blocks 0..63 : Wt[col=b][k=t] with k = h*64+c (head-major): 0.25*scl[c]*convw[c][h*64+col]
// block 64     : P[k*8+o] = scl[k]*dot(convw[k][hh*64..], att{s|d}[hh])
// block 65     : bpb[t] = sum_k sft[k]*convw[k][t];  then cs[8]
__global__ void fold2_kernel(const float* __restrict__ bnp,
                             const float* __restrict__ gamma, const float* __restrict__ beta,
                             const float* __restrict__ convw,
                             const float* __restrict__ atts, const float* __restrict__ attd,
                             _Float16* __restrict__ Wt, float* __restrict__ bpb,
                             float* __restrict__ P, float* __restrict__ cs,
                             float invN) {
    __shared__ float scl[64], sft[64], bs[256], redl[128];
    int t = threadIdx.x;
    if (t < 128) {
        const float4* bp = (const float4*)(bnp + (size_t)t * 256);
        float4 s0 = {0.f, 0.f, 0.f, 0.f}, s1 = s0, s2 = s0, s3 = s0;
#pragma unroll
        for (int i = 0; i < 16; i++) {
            float4 v0 = bp[i * 4], v1 = bp[i * 4 + 1], v2 = bp[i * 4 + 2], v3 = bp[i * 4 + 3];
            s0.x += v0.x; s0.y += v0.y; s0.z += v0.z; s0.w += v0.w;
            s1.x += v1.x; s1.y += v1.y; s1.z += v1.z; s1.w += v1.w;
            s2.x += v2.x; s2.y += v2.y; s2.z += v2.z; s2.w += v2.w;
            s3.x += v3.x; s3.y += v3.y; s3.z += v3.z; s3.w += v3.w;
        }
        redl[t] = ((s0.x + s0.y) + (s0.z + s0.w)) + ((s1.x + s1.y) + (s1.z + s1.w))
                + ((s2.x + s2.y) + (s2.z + s2.w)) + ((s3.x + s3.y) + (s3.z + s3.w));
    }
    __syncthreads();
    if (t < 64) {
        float mu = redl[t] * invN;
        float var = fmaxf(redl[64 + t] * invN - mu * mu, 0.f);
        float sc = gamma[t] / sqrtf(var + EPS_BN);
        scl[t] = sc;
        sft[t] = beta[t] - mu * sc;
    }
    __syncthreads();
    int b = blockIdx.x;
    if (b < 64) {
        int col = b;
        int h = t >> 6, c = t & 63;
        Wt[col * 256 + t] = (_Float16)(0.25f * scl[c] * convw[c * 256 + h * 64 + col]);
    } else if (b == 64) {
        for (int idx = t; idx < 512; idx += 256) {
            int k = idx >> 3, o = idx & 7, hh = o & 3;
            const float* av = (o < 4) ? atts : attd;
            float acc = 0.f;
            for (int c2 = 0; c2 < 64; c2++) acc += convw[k * 256 + hh * 64 + c2] * av[hh * 64 + c2];
            P[idx] = scl[k] * acc;
        }
    } else {
        float bacc = 0.f;
        for (int k = 0; k < 64; k++) bacc += sft[k] * convw[k * 256 + t];
        bpb[t] = bacc;
        bs[t] = bacc;
        __syncthreads();
        if (t < 8) {
            int hh = t & 3;
            const float* av = (t < 4) ? atts : attd;
            float acc = 0.f;
            for (int c2 = 0; c2 < 64; c2++) acc += bs[hh * 64 + c2] * av[hh * 64 + c2];
            cs[t] = acc;
        }
    }
}

// ============================ per-node attention logits: a_sd = h16 @ P + cs ============================
__global__ void att_node_kernel(const _Float16* __restrict__ h16, const float* __restrict__ P,
                                const float* __restrict__ cs, float* __restrict__ a_sd, int N) {
    __shared__ float As[32 * 68];
    __shared__ float Ps[512];
    __shared__ float css[8];
    int t = threadIdx.x;
    int r0 = blockIdx.x * 32;
    const f16x8* hg = (const f16x8*)(h16 + (size_t)r0 * 64);
    size_t tot8 = (size_t)N * 8;
    {
        int row = t >> 3, ch8 = (t & 7) * 8;
        size_t g8 = (size_t)r0 * 8 + t;
        f16x8 v = {};
        if (g8 < tot8) v = hg[t];
#pragma unroll
        for (int k = 0; k < 8; k++) As[row * 68 + ch8 + k] = (float)v[k];
    }
    Ps[t] = P[t];
    Ps[t + 256] = P[t + 256];
    if (t < 8) css[t] = cs[t];
    __syncthreads();
    int row = t >> 3, o = t & 7;
    int rg = r0 + row;
    if (rg >= N) return;
    float a0 = 0.f, a1 = 0.f, a2 = 0.f, a3 = 0.f;
#pragma unroll
    for (int k = 0; k < 16; k++) {
        a0 += As[row * 68 + 4 * k + 0] * Ps[(4 * k + 0) * 8 + o];
        a1 += As[row * 68 + 4 * k + 1] * Ps[(4 * k + 1) * 8 + o];
        a2 += As[row * 68 + 4 * k + 2] * Ps[(4 * k + 2) * 8 + o];
        a3 += As[row * 68 + 4 * k + 3] * Ps[(4 * k + 3) * 8 + o];
    }
    a_sd[(size_t)rg * 8 + o] = css[o] + (a0 + a1) + (a2 + a3);
}

// ============================ fused scores + aggregation + projection (MFMA) ============================
// One 16-node tile per block, 4 waves; slot = 16 lanes owns one node. Head-major k-order
// (k = head*64 + c), fp16 packed accumulation: per 4-edge chunk — score role (edge j=c4>>2,
// head=c4&3) computes one exp; agg role (chquad cq=c4>>2, head=c4&3) gets 4 ex via 4 shuffles,
// accumulates 16 channels with v_pk_fma_f16. MFMA projects [16x256]@[256x64].
// Epilogue: skip-add from h16_in, write h16_out, per-block BN partial atomics (256 slots).
__global__ __launch_bounds__(256) void msg_proj_kernel(
        const int* __restrict__ row_ptr, const int* __restrict__ src_csr,
        const _Float16* __restrict__ ae_l, const float* __restrict__ a_sd,
        const _Float16* __restrict__ h16_in,
        const _Float16* __restrict__ Wt, const float* __restrict__ bpb,
        const float* __restrict__ bias,
        _Float16* __restrict__ h16_out, float* __restrict__ bnp_out, int N) {
    __shared__ __attribute__((aligned(16))) _Float16 Aagg[16][264];
    __shared__ __attribute__((aligned(16))) float sals[16][4];
    int t = threadIdx.x;
    int wv = t >> 6, lane = t & 63;
    int colg = wv * 16 + (lane & 15);
    int kb = (lane >> 4) * 8;
    int slot = lane >> 4, c4 = lane & 15;
    int row = wv * 4 + slot;
    int n = blockIdx.x * 16 + row;
    int head = c4 & 3;       // score head AND agg head
    int j = c4 >> 2;         // score edge-in-chunk; also agg channel-quad cq
    int sb_ = lane & 48;     // slot base lane in wave

    float bpbc[4];
#pragma unroll
    for (int hh = 0; hh < 4; hh++) bpbc[hh] = bpb[hh * 64 + colg] * 0.25f;
    float bcol = bias[colg];

    union AccU { h2 p[8]; f16x8 w[2]; } Acc;
#pragma unroll
    for (int q = 0; q < 8; q++) Acc.p[q] = (h2){(_Float16)0.f, (_Float16)0.f};
    float den = 0.f;

    if (n < N) {
        int p0 = row_ptr[n], p1 = row_ptr[n + 1];
        float ad = (p0 < p1) ? a_sd[(size_t)n * 8 + 4 + head] : 0.f;
        for (int base = p0; base < p1; base += 4) {
            int rem = p1 - base;
            int ib = rem > 1 ? 1 : 0;
            int ic = rem > 2 ? 2 : ib;
            int id = rem > 3 ? 3 : ic;
            int sa = src_csr[base];
            int sbv = src_csr[base + ib];
            int scv = src_csr[base + ic];
            int sdv = src_csr[base + id];
            int jj = j < rem ? j : rem - 1;
            int mysrc = j == 0 ? sa : (j == 1 ? sbv : (j == 2 ? scv : sdv));
            float myas = a_sd[(size_t)mysrc * 8 + head];
            float aev = (float)ae_l[(size_t)(base + jj) * 4 + head];
            // independent f16 h gathers: lane's 16 channels (j doubles as cq) for 4 edges
            const f16x8* pa = (const f16x8*)(h16_in + ((size_t)sa << 6) + j * 16);
            const f16x8* pb = (const f16x8*)(h16_in + ((size_t)sbv << 6) + j * 16);
            const f16x8* pc = (const f16x8*)(h16_in + ((size_t)scv << 6) + j * 16);
            const f16x8* pd = (const f16x8*)(h16_in + ((size_t)sdv << 6) + j * 16);
            union H8 { f16x8 v; h2 p[4]; };
            H8 a0, a1, b0, b1, c0, c1, d0, d1;
            a0.v = pa[0]; a1.v = pa[1];
            b0.v = pb[0]; b1.v = pb[1];
            c0.v = pc[0]; c1.v = pc[1];
            d0.v = pd[0]; d1.v = pd[1];
            float s = myas + ad + aev;
            s = s > 0.f ? s : 0.2f * s;
            float ex = (j < rem) ? __expf(s) : 0.f;
            float e0 = __shfl(ex, sb_ + head);
            float e1 = __shfl(ex, sb_ + 4 + head);
            float e2 = __shfl(ex, sb_ + 8 + head);
            float e3 = __shfl(ex, sb_ + 12 + head);
            den += (e0 + e1) + (e2 + e3);
            _Float16 w0h = (_Float16)e0, w1h = (_Float16)e1;
            _Float16 w2h = (_Float16)e2, w3h = (_Float16)e3;
            h2 W0 = {w0h, w0h}, W1 = {w1h, w1h}, W2 = {w2h, w2h}, W3 = {w3h, w3h};
#pragma unroll
            for (int q = 0; q < 4; q++) {
                Acc.p[q] = Acc.p[q] + W0 * a0.p[q];
                Acc.p[q + 4] = Acc.p[q + 4] + W0 * a1.p[q];
            }
#pragma unroll
            for (int q = 0; q < 4; q++) {
                Acc.p[q] = Acc.p[q] + W1 * b0.p[q];
                Acc.p[q + 4] = Acc.p[q + 4] + W1 * b1.p[q];
            }
#pragma unroll
            for (int q = 0; q < 4; q++) {
                Acc.p[q] = Acc.p[q] + W2 * c0.p[q];
                Acc.p[q + 4] = Acc.p[q + 4] + W2 * c1.p[q];
            }
#pragma unroll
            for (int q = 0; q < 4; q++) {
                Acc.p[q] = Acc.p[q] + W3 * d0.p[q];
                Acc.p[q + 4] = Acc.p[q + 4] + W3 * d1.p[q];
            }
        }
    }
    {
        float invd = den > 0.f ? 1.f / (den + EPS_SM) : 0.f;
        _Float16 ih = (_Float16)invd;
        h2 IV = {ih, ih};
#pragma unroll
        for (int q = 0; q < 8; q++) Acc.p[q] = Acc.p[q] * IV;
    }
    // LDS k = head*64 + c; lane covers c = j*16 .. +15 for its head
    {
        _Float16* dst = &Aagg[row][head * 64 + j * 16];
        *(f16x8*)dst = Acc.w[0];
        *(f16x8*)(dst + 8) = Acc.w[1];
    }
    if (j == 0) sals[row][head] = den / (den + EPS_SM);
    // B fragments loaded here (overlaps LDS drain before the barrier)
    f16x8 bfrag[8];
    const _Float16* wtp = Wt + (size_t)colg * 256 + kb;
#pragma unroll
    for (int ks = 0; ks < 8; ks++) bfrag[ks] = *(const f16x8*)(wtp + ks * 32);
    __syncthreads();

    // -------- MFMA phase --------
    f32x4 acc = {0.f, 0.f, 0.f, 0.f};
    const _Float16* ap = &Aagg[lane & 15][kb];
#pragma unroll
    for (int ks = 0; ks < 8; ks++) {
        f16x8 af = *(const f16x8*)(ap + ks * 32);
        acc = __builtin_amdgcn_mfma_f32_16x16x32_f16(af, bfrag[ks], acc, 0, 0, 0);
    }
    int r0 = (lane >> 4) * 4;
    int nb0 = blockIdx.x * 16;
    float ps = 0.f, pq = 0.f;
#pragma unroll
    for (int reg = 0; reg < 4; reg++) {
        int rr = r0 + reg;
        int nn = nb0 + rr;
        if (nn < N) {
            float v = acc[reg] + sals[rr][0] * bpbc[0] + sals[rr][1] * bpbc[1]
                    + sals[rr][2] * bpbc[2] + sals[rr][3] * bpbc[3] + bcol;
            size_t idx = ((size_t)nn << 6) + colg;
            float hv = (float)h16_in[idx];
            float outv = fmaxf(v, 0.f) + hv;
            h16_out[idx] = (_Float16)outv;
            ps += outv;
            pq += outv * outv;
        }
    }
    // reduce the 4 row-quads (lanes differing in bits 4,5) -> per-col BN partial atomics
    ps += __shfl_xor(ps, 16); ps += __shfl_xor(ps, 32);
    pq += __shfl_xor(pq, 16); pq += __shfl_xor(pq, 32);
    if ((lane >> 4) == 0) {
        int slot2 = blockIdx.x & 255;
        atomicAdd(&bnp_out[(size_t)colg * 256 + slot2], ps);
        atomicAdd(&bnp_out[(size_t)(64 + colg) * 256 + slot2], pq);
    }
}

// ============================ pooling + FC head ============================
__global__ void pool_fc_kernel(const _Float16* __restrict__ h16, const int* __restrict__ gptr,
                               const float* __restrict__ fc1_w, const float* __restrict__ fc1_b,
                               const float* __restrict__ fc2_w, const float* __restrict__ fc2_b,
                               float* __restrict__ out, int G) {
    __shared__ float pool[4][64];
    int lane = threadIdx.x & 63, wv = threadIdx.x >> 6;
    int g = blockIdx.x * 4 + wv;
    float acc = 0.f;
    if (g < G) {
        int a = gptr[g], b = gptr[g + 1];
        for (int r = a; r < b; r++) acc += (float)h16[(size_t)r * 64 + lane];
    }
    pool[wv][lane] = acc;
    __syncthreads();
    float z1 = fc1_b[lane];
#pragma unroll 8
    for (int c = 0; c < 64; c++) z1 += pool[wv][c] * fc1_w[c * 64 + lane];
    z1 = fmaxf(z1, 0.f);
    float z2 = z1 * fc2_w[lane];
    z2 += __shfl_xor(z2, 1);
    z2 += __shfl_xor(z2, 2);
    z2 += __shfl_xor(z2, 4);
    z2 += __shfl_xor(z2, 8);
    z2 += __shfl_xor(z2, 16);
    z2 += __shfl_xor(z2, 32);
    if (g < G && lane == 0) out[g] = fmaxf(z2 + fc2_b[0], 0.f);
}

// ============================ host ============================
extern "C" void kernel_launch(void* const* d_in, const int* in_sizes, int n_in,
                              void* d_out, int out_size, void* d_ws, size_t ws_size,
                              hipStream_t stream) {
    const float* x         = (const float*)d_in[0];
    const int*   eindex    = (const int*)d_in[1];
    const float* edge_attr = (const float*)d_in[2];
    const int*   batch     = (const int*)d_in[3];
    const float* lin_w     = (const float*)d_in[4];
    const float* lin_b     = (const float*)d_in[5];
    const float* bn_gamma  = (const float*)d_in[6];
    const float* bn_beta   = (const float*)d_in[7];
    const float* conv_w    = (const float*)d_in[8];
    const float* conv_we   = (const float*)d_in[9];
    const float* att_src   = (const float*)d_in[10];
    const float* att_dst   = (const float*)d_in[11];
    const float* att_edge  = (const float*)d_in[12];
    const float* conv_bias = (const float*)d_in[13];
    const float* fc1_w     = (const float*)d_in[14];
    const float* fc1_b     = (const float*)d_in[15];
    const float* fc2_w     = (const float*)d_in[16];
    const float* fc2_b     = (const float*)d_in[17];
    float* out = (float*)d_out;

    int N = in_sizes[3];
    int E = in_sizes[1] / 2;
    int G = out_size;
    const int* esrc = eindex;
    const int* edst = eindex + E;

    char* wp = (char*)d_ws;
    auto carve = [&](size_t b) -> char* {
        char* p = wp;
        wp += (b + 511) & ~(size_t)511;
        return p;
    };
    _Float16*  h16b0  = (_Float16*)carve((size_t)N * 64 * 2);     // 25.6 MB
    _Float16*  h16b1  = (_Float16*)carve((size_t)N * 64 * 2);     // 25.6 MB
    float*     a_sd   = (float*)carve((size_t)N * 8 * 4);         //  6.4 MB
    _Float16*  ae_csr = (_Float16*)carve((size_t)3 * E * 4 * 2);  //  9.6 MB
    int*       src_csr= (int*)carve((size_t)E * 4);               //  1.6 MB
    int*       deg    = (int*)carve((size_t)N * 4);
    int*       row_ptr= (int*)carve((size_t)(N + 1) * 4);
    int*       cursor = (int*)carve((size_t)N * 4);
    int*       bsum   = (int*)carve(4096);
    int*       gptr   = (int*)carve((size_t)(G + 1) * 4);
    float*     bpb    = (float*)carve(256 * 4);
    float*     P      = (float*)carve(512 * 4);
    float*     cs     = (float*)carve(8 * 4);
    float*     Qm3    = (float*)carve(96 * 4);
    _Float16*  Wt     = (_Float16*)carve(64 * 256 * 2);
    float*     bnpA   = (float*)carve((size_t)4 * 128 * 256 * 4); // 512 KB (4 layer-stat bufs)

    int nb1 = (N + 255) / 256;
    int nbP = (N + 63) / 64;
    int nTiles = (N + 15) / 16;

    // zero degree + all BN partial buffers once
    zero_kernel<<<nb1, 256, 0, stream>>>(deg, N);
    zero_kernel<<<512, 256, 0, stream>>>((int*)bnpA, 4 * 128 * 256);

    // CSR + edge-attr logits + graph ranges (static across layers)
    hist_kernel<<<(E + 255) / 256, 256, 0, stream>>>(edst, deg, E);
    scan1_kernel<<<nb1, 256, 0, stream>>>(deg, row_ptr, bsum, N);
    scan2_kernel<<<1, 1024, 0, stream>>>(bsum, nb1);
    scan3_kernel<<<(N + 1 + 255) / 256, 256, 0, stream>>>(row_ptr, cursor, bsum, N, E);
    qm3_kernel<<<1, 96, 0, stream>>>(conv_we, att_edge, Qm3);
    scatter_kernel<<<(E + 255) / 256, 256, 0, stream>>>(esrc, edst, edge_attr, Qm3,
                                                        cursor, src_csr, ae_csr, E);
    gptr_kernel<<<(G + 1 + 255) / 256, 256, 0, stream>>>(batch, gptr, N, G);

    // input projection (+ BN partial atomics for layer 0)
    proj_kernel<<<nbP, 256, 0, stream>>>(x, lin_w, lin_b, h16b0, bnpA, N);

    int cur = 0;
    _Float16* h16buf[2] = {h16b0, h16b1};

    for (int l = 0; l < 3; l++) {
        _Float16* h16c = h16buf[cur];
        _Float16* h16n = h16buf[cur ^ 1];
        float* bnpIn = bnpA + (size_t)l * 128 * 256;
        float* bnpOut = bnpA + (size_t)(l + 1) * 128 * 256;
        fold2_kernel<<<66, 256, 0, stream>>>(bnpIn,
                                             bn_gamma + l * 64, bn_beta + l * 64,
                                             conv_w + (size_t)l * 64 * 256,
                                             att_src + l * 256, att_dst + l * 256,
                                             Wt, bpb, P, cs, 1.f / (float)N);
        att_node_kernel<<<(N + 31) / 32, 256, 0, stream>>>(h16c, P, cs, a_sd, N);
        msg_proj_kernel<<<nTiles, 256, 0, stream>>>(row_ptr, src_csr,
                                                    ae_csr + (size_t)l * E * 4, a_sd,
                                                    h16c, Wt, bpb, conv_bias + l * 64,
                                                    h16n, bnpOut, N);
        cur ^= 1;
    }

    pool_fc_kernel<<<(G + 3) / 4, 256, 0, stream>>>(h16buf[cur], gptr, fc1_w, fc1_b, fc2_w, fc2_b,
                                                    out, G);
}

// Round 10
// 552.232 us; speedup vs baseline: 1.1472x; 1.1472x over previous
//
#include <hip/hip_runtime.h>
#include <cmath>

#define EPS_BN 1e-5f
#define EPS_SM 1e-16f

typedef _Float16 f16x8 __attribute__((ext_vector_type(8)));
typedef _Float16 f16x4 __attribute__((ext_vector_type(4)));
typedef float f32x4 __attribute__((ext_vector_type(4)));
union F4 { float4 v; float a[4]; };

// ============================ utility: zero fill ============================
__global__ void zero_kernel(int* __restrict__ p, int n) {
    int i = blockIdx.x * 256 + threadIdx.x;
    if (i < n) p[i] = 0;
}

// ============================ CSR build ============================
__global__ void hist_kernel(const int* __restrict__ edst, int* __restrict__ deg, int E) {
    int e = blockIdx.x * 256 + threadIdx.x;
    if (e < E) atomicAdd(&deg[edst[e]], 1);
}

__global__ void scan1_kernel(const int* __restrict__ deg, int* __restrict__ row_ptr,
                             int* __restrict__ bsum, int N) {
    __shared__ int s[256];
    int t = threadIdx.x;
    int i = blockIdx.x * 256 + t;
    int v = (i < N) ? deg[i] : 0;
    s[t] = v; __syncthreads();
    for (int off = 1; off < 256; off <<= 1) {
        int x = (t >= off) ? s[t - off] : 0;
        __syncthreads();
        s[t] += x;
        __syncthreads();
    }
    if (i < N) row_ptr[i] = s[t] - v;   // exclusive partial
    if (t == 255) bsum[blockIdx.x] = s[t];
}

__global__ void scan2_kernel(int* __restrict__ bsum, int nb) {
    __shared__ int s[1024];
    int t = threadIdx.x;
    int v = (t < nb) ? bsum[t] : 0;
    s[t] = v; __syncthreads();
    for (int off = 1; off < 1024; off <<= 1) {
        int x = (t >= off) ? s[t - off] : 0;
        __syncthreads();
        s[t] += x;
        __syncthreads();
    }
    if (t < nb) bsum[t] = s[t] - v;     // exclusive
}

__global__ void scan3_kernel(int* __restrict__ row_ptr, int* __restrict__ cursor,
                             const int* __restrict__ bsum, int N, int E) {
    int i = blockIdx.x * 256 + threadIdx.x;
    if (i < N) {
        int v = row_ptr[i] + bsum[blockIdx.x];
        row_ptr[i] = v;
        cursor[i] = v;
    } else if (i == N) {
        row_ptr[N] = E;
    }
}

// Qm3[l][f*4+hh] = sum_c conv_we[l][f][hh*64+c] * att_edge[l][hh][c]   (BN-independent)
__global__ void qm3_kernel(const float* __restrict__ convwe, const float* __restrict__ atte,
                           float* __restrict__ Qm3) {
    int t = threadIdx.x;
    if (t >= 96) return;
    int l = t >> 5, f = (t >> 2) & 7, hh = t & 3;
    const float* we = convwe + (size_t)l * 8 * 256;
    const float* av = atte + (size_t)l * 256;
    float acc = 0.f;
    for (int c = 0; c < 64; c++) acc += we[f * 256 + hh * 64 + c] * av[hh * 64 + c];
    Qm3[t] = acc;
}

// scatter edges to CSR order: src_csr[p] = src, ae_csr[l][p][4] = f16(edge_attr@Qm3[l])
__global__ void scatter_kernel(const int* __restrict__ esrc, const int* __restrict__ edst,
                               const float* __restrict__ edge_attr, const float* __restrict__ Qm3,
                               int* __restrict__ cursor, int* __restrict__ src_csr,
                               _Float16* __restrict__ ae_csr, int E) {
    __shared__ float q[96];
    int t = threadIdx.x;
    if (t < 96) q[t] = Qm3[t];
    __syncthreads();
    int e = blockIdx.x * 256 + t;
    if (e >= E) return;
    int src = esrc[e];
    int p = atomicAdd(&cursor[edst[e]], 1);
    src_csr[p] = src;
    F4 ea0, ea1;
    ea0.v = ((const float4*)edge_attr)[(size_t)e * 2];
    ea1.v = ((const float4*)edge_attr)[(size_t)e * 2 + 1];
#pragma unroll
    for (int l = 0; l < 3; l++) {
        const float* ql = q + l * 32;
        f16x4 r;
#pragma unroll
        for (int hh = 0; hh < 4; hh++) {
            float acc = ea0.a[0] * ql[0 * 4 + hh] + ea0.a[1] * ql[1 * 4 + hh]
                      + ea0.a[2] * ql[2 * 4 + hh] + ea0.a[3] * ql[3 * 4 + hh]
                      + ea1.a[0] * ql[4 * 4 + hh] + ea1.a[1] * ql[5 * 4 + hh]
                      + ea1.a[2] * ql[6 * 4 + hh] + ea1.a[3] * ql[7 * 4 + hh];
            r[hh] = (_Float16)acc;
        }
        *(f16x4*)(ae_csr + ((size_t)l * E + p) * 4) = r;
    }
}

// graph ranges by binary search (batch is sorted)
__global__ void gptr_kernel(const int* __restrict__ batch, int* __restrict__ gptr, int N, int G) {
    int g = blockIdx.x * 256 + threadIdx.x;
    if (g > G) return;
    int lo = 0, hi = N;
    while (lo < hi) { int mid = (lo + hi) >> 1; if (batch[mid] < g) lo = mid + 1; else hi = mid; }
    gptr[g] = lo;
}

// ============================ input projection (h16 + BN partials) ============================
__global__ void proj_kernel(const float* __restrict__ x, const float* __restrict__ lin_w,
                            const float* __restrict__ lin_b,
                            _Float16* __restrict__ h16, float* __restrict__ bnpart, int N) {
    __shared__ float Xs[64 * 32];
    __shared__ float ls[256], lq[256];
    int t = threadIdx.x;
    int col = t & 63, sub = t >> 6;
    float w[32];
#pragma unroll
    for (int k = 0; k < 32; k++) w[k] = lin_w[k * 64 + col];
    float b = lin_b[col];
    int r0 = blockIdx.x * 64;
    const float4* xg = (const float4*)(x + (size_t)r0 * 32);
    float4* Xs4 = (float4*)Xs;
    size_t totf4 = (size_t)N * 8;
#pragma unroll
    for (int i = 0; i < 2; i++) {
        int idx = t + i * 256;
        size_t gidx = (size_t)r0 * 8 + idx;
        Xs4[idx] = (gidx < totf4) ? xg[idx] : make_float4(0.f, 0.f, 0.f, 0.f);
    }
    __syncthreads();
    float ps = 0.f, pq = 0.f;
    for (int rr = sub; rr < 64; rr += 4) {
        int r = r0 + rr;
        if (r >= N) break;
        float acc = b;
        const float4* a4p = (const float4*)(Xs + rr * 32);
#pragma unroll
        for (int kk = 0; kk < 8; kk++) {
            float4 a4 = a4p[kk];
            acc += a4.x * w[kk * 4] + a4.y * w[kk * 4 + 1] + a4.z * w[kk * 4 + 2] + a4.w * w[kk * 4 + 3];
        }
        float hv = fmaxf(acc, 0.f);
        h16[(size_t)r * 64 + col] = (_Float16)hv;
        ps += hv; pq += hv * hv;
    }
    ls[t] = ps; lq[t] = pq;
    __syncthreads();
    if (t < 64) {
        bnpart[(size_t)blockIdx.x * 128 + t] = ls[t] + ls[t + 64] + ls[t + 128] + ls[t + 192];
        bnpart[(size_t)blockIdx.x * 128 + 64 + t] = lq[t] + lq[t + 64] + lq[t + 128] + lq[t + 192];
    }
}

// reduce bnpart over blocks: red[stat] = sum_b bnpart[b][stat], stat = blockIdx (128 blocks)
__global__ void bn_reduce_kernel(const float* __restrict__ bnpart, int nb, float* __restrict__ red) {
    __shared__ float s[256];
    int stat = blockIdx.x;
    float acc = 0.f;
    for (int j = threadIdx.x; j < nb; j += 256) acc += bnpart[(size_t)j * 128 + stat];
    s[threadIdx.x] = acc;
    __syncthreads();
    for (int off = 128; off >= 1; off >>= 1) {
        if (threadIdx.x < off) s[threadIdx.x] += s[threadIdx.x + off];
        __syncthreads();
    }
    if (threadIdx.x == 0) red[stat] = s[0];
}

// ============================ fold (parallel) ============================
__global__ void fold2_kernel(const float* __restrict__ red,
                             const float* __restrict__ gamma, const float* __restrict__ beta,
                             const float* __restrict__ convw,
                             const float* __restrict__ atts, const float* __restrict__ attd,
                             _Float16* __restrict__ Wt, float* __restrict__ bpb,
                             float* __restrict__ P, float* __restrict__ cs,
                             float invN) {
    __shared__ float scl[64], sft[64], bs[256];
    int t = threadIdx.x;
    if (t < 64) {
        float mu = red[t] * invN;
        float var = fmaxf(red[64 + t] * invN - mu * mu, 0.f);
        float sc = gamma[t] / sqrtf(var + EPS_BN);
        scl[t] = sc;
        sft[t] = beta[t] - mu * sc;
    }
    __syncthreads();
    int b = blockIdx.x;
    if (b < 64) {
        int col = b;
        int c = t >> 2, hh = t & 3;
        Wt[col * 256 + t] = (_Float16)(0.25f * scl[c] * convw[c * 256 + hh * 64 + col]);
    } else if (b == 64) {
        for (int idx = t; idx < 512; idx += 256) {
            int k = idx >> 3, o = idx & 7, hh = o & 3;
            const float* av = (o < 4) ? atts : attd;
            float acc = 0.f;
            for (int c2 = 0; c2 < 64; c2++) acc += convw[k * 256 + hh * 64 + c2] * av[hh * 64 + c2];
            P[idx] = scl[k] * acc;
        }
    } else {
        float bacc = 0.f;
        for (int k = 0; k < 64; k++) bacc += sft[k] * convw[k * 256 + t];
        bpb[t] = bacc;
        bs[t] = bacc;
        __syncthreads();
        if (t < 8) {
            int hh = t & 3;
            const float* av = (t < 4) ? atts : attd;
            float acc = 0.f;
            for (int c2 = 0; c2 < 64; c2++) acc += bs[hh * 64 + c2] * av[hh * 64 + c2];
            cs[t] = acc;
        }
    }
}

// ============================ per-node attention logits: a_sd = h16 @ P + cs ============================
__global__ void att_node_kernel(const _Float16* __restrict__ h16, const float* __restrict__ P,
                                const float* __restrict__ cs, float* __restrict__ a_sd, int N) {
    __shared__ float As[32 * 68];
    __shared__ float Ps[512];
    __shared__ float css[8];
    int t = threadIdx.x;
    int r0 = blockIdx.x * 32;
    const f16x8* hg = (const f16x8*)(h16 + (size_t)r0 * 64);
    size_t tot8 = (size_t)N * 8;
    {
        int row = t >> 3, ch8 = (t & 7) * 8;
        size_t g8 = (size_t)r0 * 8 + t;
        f16x8 v = {};
        if (g8 < tot8) v = hg[t];
#pragma unroll
        for (int k = 0; k < 8; k++) As[row * 68 + ch8 + k] = (float)v[k];
    }
    Ps[t] = P[t];
    Ps[t + 256] = P[t + 256];
    if (t < 8) css[t] = cs[t];
    __syncthreads();
    int row = t >> 3, o = t & 7;
    int rg = r0 + row;
    if (rg >= N) return;
    float a0 = 0.f, a1 = 0.f, a2 = 0.f, a3 = 0.f;
#pragma unroll
    for (int k = 0; k < 16; k++) {
        a0 += As[row * 68 + 4 * k + 0] * Ps[(4 * k + 0) * 8 + o];
        a1 += As[row * 68 + 4 * k + 1] * Ps[(4 * k + 1) * 8 + o];
        a2 += As[row * 68 + 4 * k + 2] * Ps[(4 * k + 2) * 8 + o];
        a3 += As[row * 68 + 4 * k + 3] * Ps[(4 * k + 3) * 8 + o];
    }
    a_sd[(size_t)rg * 8 + o] = css[o] + (a0 + a1) + (a2 + a3);
}

// ============================ fused scores + aggregation + projection (MFMA) ============================
// 32-node tile per block, 4 waves; slot = 16 lanes owns TWO nodes (rows wv*8+slot and +4),
// whose edge chunks are processed interleaved in one loop -> 8 independent gather chains
// per wave. Per 4-edge chunk (per node): 4 clamped src prefetch, 4 independent f16 h-row
// gathers, per-lane score gather + exp, intra-slot shuffle broadcast, fp32 accumulation.
// MFMA projects two [16x256]@[256x64] tiles. Epilogue: skip-add, h16 write, BN partials.
__global__ __launch_bounds__(256) void msg_proj_kernel(
        const int* __restrict__ row_ptr, const int* __restrict__ src_csr,
        const _Float16* __restrict__ ae_l, const float* __restrict__ a_sd,
        const _Float16* __restrict__ h16_in,
        const _Float16* __restrict__ Wt, const float* __restrict__ bpb,
        const float* __restrict__ bias,
        _Float16* __restrict__ h16_out, float* __restrict__ bnpart, int N) {
    __shared__ __attribute__((aligned(16))) _Float16 Aagg[32][264];
    __shared__ __attribute__((aligned(16))) float sals[32][4];
    int t = threadIdx.x;
    int wv = t >> 6, lane = t & 63;
    int colg = wv * 16 + (lane & 15);
    int kb = (lane >> 4) * 8;
    int slot = lane >> 4, c4 = lane & 15;
    int head = c4 & 3, j = c4 >> 2;
    int sb_ = lane & 48;   // slot base lane in wave
    int nb0 = blockIdx.x * 32;
    int rows[2] = {wv * 8 + slot, wv * 8 + slot + 4};

    float bpbc[4];
#pragma unroll
    for (int hh = 0; hh < 4; hh++) bpbc[hh] = bpb[hh * 64 + colg] * 0.25f;
    float bcol = bias[colg];

    float4 AA[2][4];
    float dd[2][4];
    int p1v[2];
    float adv[2];
    int base0, base1;
#pragma unroll
    for (int u = 0; u < 2; u++) {
#pragma unroll
        for (int q = 0; q < 4; q++) { AA[u][q] = make_float4(0.f, 0.f, 0.f, 0.f); dd[u][q] = 0.f; }
        int n = nb0 + rows[u];
        int p0 = 0, p1 = 0;
        if (n < N) { p0 = row_ptr[n]; p1 = row_ptr[n + 1]; }
        adv[u] = (p0 < p1) ? a_sd[(size_t)n * 8 + 4 + head] : 0.f;
        p1v[u] = p1;
        if (u == 0) base0 = p0; else base1 = p0;
    }

    auto chunk = [&](int u, int base) {
        int rem = p1v[u] - base;
        int ib = rem > 1 ? 1 : 0;
        int ic = rem > 2 ? 2 : ib;
        int id = rem > 3 ? 3 : ic;
        int sa = src_csr[base];
        int sbv = src_csr[base + ib];
        int scv = src_csr[base + ic];
        int sdv = src_csr[base + id];
        int jj = j < rem ? j : rem - 1;
        int mysrc = j == 0 ? sa : (j == 1 ? sbv : (j == 2 ? scv : sdv));
        float myas = a_sd[(size_t)mysrc * 8 + head];
        float aev = (float)ae_l[(size_t)(base + jj) * 4 + head];
        f16x4 hah = *(const f16x4*)(h16_in + ((size_t)sa << 6) + (c4 << 2));
        f16x4 hbh = *(const f16x4*)(h16_in + ((size_t)sbv << 6) + (c4 << 2));
        f16x4 hch = *(const f16x4*)(h16_in + ((size_t)scv << 6) + (c4 << 2));
        f16x4 hdh = *(const f16x4*)(h16_in + ((size_t)sdv << 6) + (c4 << 2));
        float s = myas + adv[u] + aev;
        s = s > 0.f ? s : 0.2f * s;
        float ex = (j < rem) ? __expf(s) : 0.f;
        float ea0 = __shfl(ex, sb_ + 0), ea1 = __shfl(ex, sb_ + 1);
        float ea2 = __shfl(ex, sb_ + 2), ea3 = __shfl(ex, sb_ + 3);
        float eb0 = __shfl(ex, sb_ + 4), eb1 = __shfl(ex, sb_ + 5);
        float eb2 = __shfl(ex, sb_ + 6), eb3 = __shfl(ex, sb_ + 7);
        float ec0 = __shfl(ex, sb_ + 8), ec1 = __shfl(ex, sb_ + 9);
        float ec2 = __shfl(ex, sb_ + 10), ec3 = __shfl(ex, sb_ + 11);
        float ed0 = __shfl(ex, sb_ + 12), ed1 = __shfl(ex, sb_ + 13);
        float ed2 = __shfl(ex, sb_ + 14), ed3 = __shfl(ex, sb_ + 15);
        float4 ha = {(float)hah[0], (float)hah[1], (float)hah[2], (float)hah[3]};
        float4 hb = {(float)hbh[0], (float)hbh[1], (float)hbh[2], (float)hbh[3]};
        float4 hc = {(float)hch[0], (float)hch[1], (float)hch[2], (float)hch[3]};
        float4 hd = {(float)hdh[0], (float)hdh[1], (float)hdh[2], (float)hdh[3]};
        AA[u][0].x = fmaf(ea0, ha.x, fmaf(eb0, hb.x, fmaf(ec0, hc.x, fmaf(ed0, hd.x, AA[u][0].x))));
        AA[u][0].y = fmaf(ea0, ha.y, fmaf(eb0, hb.y, fmaf(ec0, hc.y, fmaf(ed0, hd.y, AA[u][0].y))));
        AA[u][0].z = fmaf(ea0, ha.z, fmaf(eb0, hb.z, fmaf(ec0, hc.z, fmaf(ed0, hd.z, AA[u][0].z))));
        AA[u][0].w = fmaf(ea0, ha.w, fmaf(eb0, hb.w, fmaf(ec0, hc.w, fmaf(ed0, hd.w, AA[u][0].w))));
        AA[u][1].x = fmaf(ea1, ha.x, fmaf(eb1, hb.x, fmaf(ec1, hc.x, fmaf(ed1, hd.x, AA[u][1].x))));
        AA[u][1].y = fmaf(ea1, ha.y, fmaf(eb1, hb.y, fmaf(ec1, hc.y, fmaf(ed1, hd.y, AA[u][1].y))));
        AA[u][1].z = fmaf(ea1, ha.z, fmaf(eb1, hb.z, fmaf(ec1, hc.z, fmaf(ed1, hd.z, AA[u][1].z))));
        AA[u][1].w = fmaf(ea1, ha.w, fmaf(eb1, hb.w, fmaf(ec1, hc.w, fmaf(ed1, hd.w, AA[u][1].w))));
        AA[u][2].x = fmaf(ea2, ha.x, fmaf(eb2, hb.x, fmaf(ec2, hc.x, fmaf(ed2, hd.x, AA[u][2].x))));
        AA[u][2].y = fmaf(ea2, ha.y, fmaf(eb2, hb.y, fmaf(ec2, hc.y, fmaf(ed2, hd.y, AA[u][2].y))));
        AA[u][2].z = fmaf(ea2, ha.z, fmaf(eb2, hb.z, fmaf(ec2, hc.z, fmaf(ed2, hd.z, AA[u][2].z))));
        AA[u][2].w = fmaf(ea2, ha.w, fmaf(eb2, hb.w, fmaf(ec2, hc.w, fmaf(ed2, hd.w, AA[u][2].w))));
        AA[u][3].x = fmaf(ea3, ha.x, fmaf(eb3, hb.x, fmaf(ec3, hc.x, fmaf(ed3, hd.x, AA[u][3].x))));
        AA[u][3].y = fmaf(ea3, ha.y, fmaf(eb3, hb.y, fmaf(ec3, hc.y, fmaf(ed3, hd.y, AA[u][3].y))));
        AA[u][3].z = fmaf(ea3, ha.z, fmaf(eb3, hb.z, fmaf(ec3, hc.z, fmaf(ed3, hd.z, AA[u][3].z))));
        AA[u][3].w = fmaf(ea3, ha.w, fmaf(eb3, hb.w, fmaf(ec3, hc.w, fmaf(ed3, hd.w, AA[u][3].w))));
        dd[u][0] += (ea0 + eb0) + (ec0 + ed0);
        dd[u][1] += (ea1 + eb1) + (ec1 + ed1);
        dd[u][2] += (ea2 + eb2) + (ec2 + ed2);
        dd[u][3] += (ea3 + eb3) + (ec3 + ed3);
    };

    while (base0 < p1v[0] || base1 < p1v[1]) {
        if (base0 < p1v[0]) chunk(0, base0);
        if (base1 < p1v[1]) chunk(1, base1);
        base0 += 4; base1 += 4;
    }

#pragma unroll
    for (int u = 0; u < 2; u++) {
        float i0 = 1.f / (dd[u][0] + EPS_SM), i1 = 1.f / (dd[u][1] + EPS_SM);
        float i2 = 1.f / (dd[u][2] + EPS_SM), i3 = 1.f / (dd[u][3] + EPS_SM);
        f16x8 v0, v1;
        const float* a0 = (const float*)&AA[u][0];
        const float* a1 = (const float*)&AA[u][1];
        const float* a2 = (const float*)&AA[u][2];
        const float* a3 = (const float*)&AA[u][3];
#pragma unroll
        for (int cc = 0; cc < 2; cc++) {
            v0[cc * 4 + 0] = (_Float16)(a0[cc] * i0);
            v0[cc * 4 + 1] = (_Float16)(a1[cc] * i1);
            v0[cc * 4 + 2] = (_Float16)(a2[cc] * i2);
            v0[cc * 4 + 3] = (_Float16)(a3[cc] * i3);
        }
#pragma unroll
        for (int cc = 0; cc < 2; cc++) {
            v1[cc * 4 + 0] = (_Float16)(a0[cc + 2] * i0);
            v1[cc * 4 + 1] = (_Float16)(a1[cc + 2] * i1);
            v1[cc * 4 + 2] = (_Float16)(a2[cc + 2] * i2);
            v1[cc * 4 + 3] = (_Float16)(a3[cc + 2] * i3);
        }
        *(f16x8*)&Aagg[rows[u]][c4 * 16] = v0;
        *(f16x8*)&Aagg[rows[u]][c4 * 16 + 8] = v1;
        if (c4 == 0) {
            float4 sv;
            sv.x = dd[u][0] / (dd[u][0] + EPS_SM);
            sv.y = dd[u][1] / (dd[u][1] + EPS_SM);
            sv.z = dd[u][2] / (dd[u][2] + EPS_SM);
            sv.w = dd[u][3] / (dd[u][3] + EPS_SM);
            *(float4*)&sals[rows[u]][0] = sv;
        }
    }
    // B fragments loaded here (overlaps LDS drain before the barrier)
    f16x8 bfrag[8];
    const _Float16* wtp = Wt + (size_t)colg * 256 + kb;
#pragma unroll
    for (int ks = 0; ks < 8; ks++) bfrag[ks] = *(const f16x8*)(wtp + ks * 32);
    __syncthreads();

    // -------- MFMA phase: two 16-row tiles --------
    float ps = 0.f, pq = 0.f;
#pragma unroll
    for (int half = 0; half < 2; half++) {
        f32x4 acc = {0.f, 0.f, 0.f, 0.f};
        const _Float16* ap = &Aagg[half * 16 + (lane & 15)][kb];
#pragma unroll
        for (int ks = 0; ks < 8; ks++) {
            f16x8 af = *(const f16x8*)(ap + ks * 32);
            acc = __builtin_amdgcn_mfma_f32_16x16x32_f16(af, bfrag[ks], acc, 0, 0, 0);
        }
        int r0 = half * 16 + (lane >> 4) * 4;
#pragma unroll
        for (int reg = 0; reg < 4; reg++) {
            int rr = r0 + reg;
            int nn = nb0 + rr;
            if (nn < N) {
                float v = acc[reg] + sals[rr][0] * bpbc[0] + sals[rr][1] * bpbc[1]
                        + sals[rr][2] * bpbc[2] + sals[rr][3] * bpbc[3] + bcol;
                size_t idx = ((size_t)nn << 6) + colg;
                float hv = (float)h16_in[idx];
                float outv = fmaxf(v, 0.f) + hv;
                h16_out[idx] = (_Float16)outv;
                ps += outv;
                pq += outv * outv;
            }
        }
    }
    // reduce the 4 row-quads (lanes differing in bits 4,5) -> per-col BN partials
    ps += __shfl_xor(ps, 16); ps += __shfl_xor(ps, 32);
    pq += __shfl_xor(pq, 16); pq += __shfl_xor(pq, 32);
    if ((lane >> 4) == 0) {
        bnpart[(size_t)blockIdx.x * 128 + colg] = ps;
        bnpart[(size_t)blockIdx.x * 128 + 64 + colg] = pq;
    }
}

// ============================ pooling + FC head ============================
__global__ void pool_fc_kernel(const _Float16* __restrict__ h16, const int* __restrict__ gptr,
                               const float* __restrict__ fc1_w, const float* __restrict__ fc1_b,
                               const float* __restrict__ fc2_w, const float* __restrict__ fc2_b,
                               float* __restrict__ out, int G) {
    __shared__ float pool[4][64];
    int lane = threadIdx.x & 63, wv = threadIdx.x >> 6;
    int g = blockIdx.x * 4 + wv;
    float acc = 0.f;
    if (g < G) {
        int a = gptr[g], b = gptr[g + 1];
        for (int r = a; r < b; r++) acc += (float)h16[(size_t)r * 64 + lane];
    }
    pool[wv][lane] = acc;
    __syncthreads();
    float z1 = fc1_b[lane];
#pragma unroll 8
    for (int c = 0; c < 64; c++) z1 += pool[wv][c] * fc1_w[c * 64 + lane];
    z1 = fmaxf(z1, 0.f);
    float z2 = z1 * fc2_w[lane];
    z2 += __shfl_xor(z2, 1);
    z2 += __shfl_xor(z2, 2);
    z2 += __shfl_xor(z2, 4);
    z2 += __shfl_xor(z2, 8);
    z2 += __shfl_xor(z2, 16);
    z2 += __shfl_xor(z2, 32);
    if (g < G && lane == 0) out[g] = fmaxf(z2 + fc2_b[0], 0.f);
}

// ============================ host ============================
extern "C" void kernel_launch(void* const* d_in, const int* in_sizes, int n_in,
                              void* d_out, int out_size, void* d_ws, size_t ws_size,
                              hipStream_t stream) {
    const float* x         = (const float*)d_in[0];
    const int*   eindex    = (const int*)d_in[1];
    const float* edge_attr = (const float*)d_in[2];
    const int*   batch     = (const int*)d_in[3];
    const float* lin_w     = (const float*)d_in[4];
    const float* lin_b     = (const float*)d_in[5];
    const float* bn_gamma  = (const float*)d_in[6];
    const float* bn_beta   = (const float*)d_in[7];
    const float* conv_w    = (const float*)d_in[8];
    const float* conv_we   = (const float*)d_in[9];
    const float* att_src   = (const float*)d_in[10];
    const float* att_dst   = (const float*)d_in[11];
    const float* att_edge  = (const float*)d_in[12];
    const float* conv_bias = (const float*)d_in[13];
    const float* fc1_w     = (const float*)d_in[14];
    const float* fc1_b     = (const float*)d_in[15];
    const float* fc2_w     = (const float*)d_in[16];
    const float* fc2_b     = (const float*)d_in[17];
    float* out = (float*)d_out;

    int N = in_sizes[3];
    int E = in_sizes[1] / 2;
    int G = out_size;
    const int* esrc = eindex;
    const int* edst = eindex + E;

    char* wp = (char*)d_ws;
    auto carve = [&](size_t b) -> char* {
        char* p = wp;
        wp += (b + 511) & ~(size_t)511;
        return p;
    };
    _Float16*  h16b0  = (_Float16*)carve((size_t)N * 64 * 2);     // 25.6 MB
    _Float16*  h16b1  = (_Float16*)carve((size_t)N * 64 * 2);     // 25.6 MB
    float*     a_sd   = (float*)carve((size_t)N * 8 * 4);         //  6.4 MB
    _Float16*  ae_csr = (_Float16*)carve((size_t)3 * E * 4 * 2);  //  9.6 MB
    int*       src_csr= (int*)carve((size_t)E * 4);               //  1.6 MB
    int*       deg    = (int*)carve((size_t)N * 4);
    int*       row_ptr= (int*)carve((size_t)(N + 1) * 4);
    int*       cursor = (int*)carve((size_t)N * 4);
    int*       bsum   = (int*)carve(4096);
    int*       gptr   = (int*)carve((size_t)(G + 1) * 4);
    float*     bpb    = (float*)carve(256 * 4);
    float*     P      = (float*)carve(512 * 4);
    float*     cs     = (float*)carve(8 * 4);
    float*     Qm3    = (float*)carve(96 * 4);
    _Float16*  Wt     = (_Float16*)carve(64 * 256 * 2);
    float*     red    = (float*)carve(128 * 4);
    int nb1 = (N + 255) / 256;
    int nbP = (N + 63) / 64;
    int nTiles = (N + 31) / 32;
    int maxPart = nbP > nTiles ? nbP : nTiles;
    float*     bnpart = (float*)carve((size_t)maxPart * 128 * 4);

    // CSR + edge-attr logits + graph ranges (static across layers)
    zero_kernel<<<nb1, 256, 0, stream>>>(deg, N);
    hist_kernel<<<(E + 255) / 256, 256, 0, stream>>>(edst, deg, E);
    scan1_kernel<<<nb1, 256, 0, stream>>>(deg, row_ptr, bsum, N);
    scan2_kernel<<<1, 1024, 0, stream>>>(bsum, nb1);
    scan3_kernel<<<(N + 1 + 255) / 256, 256, 0, stream>>>(row_ptr, cursor, bsum, N, E);
    qm3_kernel<<<1, 96, 0, stream>>>(conv_we, att_edge, Qm3);
    scatter_kernel<<<(E + 255) / 256, 256, 0, stream>>>(esrc, edst, edge_attr, Qm3,
                                                        cursor, src_csr, ae_csr, E);
    gptr_kernel<<<(G + 1 + 255) / 256, 256, 0, stream>>>(batch, gptr, N, G);

    // input projection (+ BN partials for layer 0)
    proj_kernel<<<nbP, 256, 0, stream>>>(x, lin_w, lin_b, h16b0, bnpart, N);

    int cur = 0;
    _Float16* h16buf[2] = {h16b0, h16b1};
    int nbPart = nbP;   // partial count for current layer's BN

    for (int l = 0; l < 3; l++) {
        _Float16* h16c = h16buf[cur];
        _Float16* h16n = h16buf[cur ^ 1];
        bn_reduce_kernel<<<128, 256, 0, stream>>>(bnpart, nbPart, red);
        fold2_kernel<<<66, 256, 0, stream>>>(red,
                                             bn_gamma + l * 64, bn_beta + l * 64,
                                             conv_w + (size_t)l * 64 * 256,
                                             att_src + l * 256, att_dst + l * 256,
                                             Wt, bpb, P, cs, 1.f / (float)N);
        att_node_kernel<<<(N + 31) / 32, 256, 0, stream>>>(h16c, P, cs, a_sd, N);
        msg_proj_kernel<<<nTiles, 256, 0, stream>>>(row_ptr, src_csr,
                                                    ae_csr + (size_t)l * E * 4, a_sd,
                                                    h16c, Wt, bpb, conv_bias + l * 64,
                                                    h16n, bnpart, N);
        nbPart = nTiles;
        cur ^= 1;
    }

    pool_fc_kernel<<<(G + 3) / 4, 256, 0, stream>>>(h16buf[cur], gptr, fc1_w, fc1_b, fc2_w, fc2_b,
                                                    out, G);
}

// Round 11
// 509.497 us; speedup vs baseline: 1.2435x; 1.0839x over previous
//
#include <hip/hip_runtime.h>
#include <cmath>

#define EPS_BN 1e-5f
#define EPS_SM 1e-16f

typedef _Float16 f16x8 __attribute__((ext_vector_type(8)));
typedef _Float16 f16x4 __attribute__((ext_vector_type(4)));
typedef _Float16 h2 __attribute__((ext_vector_type(2)));
typedef float f32x4 __attribute__((ext_vector_type(4)));
typedef int int4u __attribute__((ext_vector_type(4), aligned(4)));
union F4 { float4 v; float a[4]; };

// ============================ CSR build ============================
__global__ void hist_kernel(const int* __restrict__ edst, int* __restrict__ deg, int E) {
    int e = blockIdx.x * 256 + threadIdx.x;
    if (e < E) atomicAdd(&deg[edst[e]], 1);
}

__global__ void scan1_kernel(const int* __restrict__ deg, int* __restrict__ row_ptr,
                             int* __restrict__ bsum, int N) {
    __shared__ int s[256];
    int t = threadIdx.x;
    int i = blockIdx.x * 256 + t;
    int v = (i < N) ? deg[i] : 0;
    s[t] = v; __syncthreads();
    for (int off = 1; off < 256; off <<= 1) {
        int x = (t >= off) ? s[t - off] : 0;
        __syncthreads();
        s[t] += x;
        __syncthreads();
    }
    if (i < N) row_ptr[i] = s[t] - v;   // exclusive partial
    if (t == 255) bsum[blockIdx.x] = s[t];
}

__global__ void scan2_kernel(int* __restrict__ bsum, int nb) {
    __shared__ int s[1024];
    int t = threadIdx.x;
    int v = (t < nb) ? bsum[t] : 0;
    s[t] = v; __syncthreads();
    for (int off = 1; off < 1024; off <<= 1) {
        int x = (t >= off) ? s[t - off] : 0;
        __syncthreads();
        s[t] += x;
        __syncthreads();
    }
    if (t < nb) bsum[t] = s[t] - v;     // exclusive
}

__global__ void scan3_kernel(int* __restrict__ row_ptr, int* __restrict__ cursor,
                             const int* __restrict__ bsum, int N, int E) {
    int i = blockIdx.x * 256 + threadIdx.x;
    if (i < N) {
        int v = row_ptr[i] + bsum[blockIdx.x];
        row_ptr[i] = v;
        cursor[i] = v;
    } else if (i == N) {
        row_ptr[N] = E;
    }
}

// ============================ merged setup: zero deg | Qm3 | gptr ============================
// blocks [0, nb1): zero deg; block nb1: Qm3; blocks (nb1, ...]: gptr binary search
__global__ void setup_kernel(int* __restrict__ deg, int N, int nb1,
                             const float* __restrict__ convwe, const float* __restrict__ atte,
                             float* __restrict__ Qm3,
                             const int* __restrict__ batch, int* __restrict__ gptr, int G) {
    int b = blockIdx.x;
    int t = threadIdx.x;
    if (b < nb1) {
        int i = b * 256 + t;
        if (i < N) deg[i] = 0;
    } else if (b == nb1) {
        if (t >= 96) return;
        int l = t >> 5, f = (t >> 2) & 7, hh = t & 3;
        const float* we = convwe + (size_t)l * 8 * 256;
        const float* av = atte + (size_t)l * 256;
        float acc = 0.f;
        for (int c = 0; c < 64; c++) acc += we[f * 256 + hh * 64 + c] * av[hh * 64 + c];
        Qm3[t] = acc;
    } else {
        int g = (b - nb1 - 1) * 256 + t;
        if (g > G) return;
        int lo = 0, hi = N;
        while (lo < hi) { int mid = (lo + hi) >> 1; if (batch[mid] < g) lo = mid + 1; else hi = mid; }
        gptr[g] = lo;
    }
}

// scatter edges to CSR order: src_csr[p] = src, ae_csr[l][p][4] = f16(edge_attr@Qm3[l])
__global__ void scatter_kernel(const int* __restrict__ esrc, const int* __restrict__ edst,
                               const float* __restrict__ edge_attr, const float* __restrict__ Qm3,
                               int* __restrict__ cursor, int* __restrict__ src_csr,
                               _Float16* __restrict__ ae_csr, int E) {
    __shared__ float q[96];
    int t = threadIdx.x;
    if (t < 96) q[t] = Qm3[t];
    __syncthreads();
    int e = blockIdx.x * 256 + t;
    if (e >= E) return;
    int src = esrc[e];
    int p = atomicAdd(&cursor[edst[e]], 1);
    src_csr[p] = src;
    F4 ea0, ea1;
    ea0.v = ((const float4*)edge_attr)[(size_t)e * 2];
    ea1.v = ((const float4*)edge_attr)[(size_t)e * 2 + 1];
#pragma unroll
    for (int l = 0; l < 3; l++) {
        const float* ql = q + l * 32;
        f16x4 r;
#pragma unroll
        for (int hh = 0; hh < 4; hh++) {
            float acc = ea0.a[0] * ql[0 * 4 + hh] + ea0.a[1] * ql[1 * 4 + hh]
                      + ea0.a[2] * ql[2 * 4 + hh] + ea0.a[3] * ql[3 * 4 + hh]
                      + ea1.a[0] * ql[4 * 4 + hh] + ea1.a[1] * ql[5 * 4 + hh]
                      + ea1.a[2] * ql[6 * 4 + hh] + ea1.a[3] * ql[7 * 4 + hh];
            r[hh] = (_Float16)acc;
        }
        *(f16x4*)(ae_csr + ((size_t)l * E + p) * 4) = r;
    }
}

// ============================ input projection (h16 + BN partials) ============================
__global__ void proj_kernel(const float* __restrict__ x, const float* __restrict__ lin_w,
                            const float* __restrict__ lin_b,
                            _Float16* __restrict__ h16, float* __restrict__ bnpart, int N) {
    __shared__ float Xs[64 * 32];
    __shared__ float ls[256], lq[256];
    int t = threadIdx.x;
    int col = t & 63, sub = t >> 6;
    float w[32];
#pragma unroll
    for (int k = 0; k < 32; k++) w[k] = lin_w[k * 64 + col];
    float b = lin_b[col];
    int r0 = blockIdx.x * 64;
    const float4* xg = (const float4*)(x + (size_t)r0 * 32);
    float4* Xs4 = (float4*)Xs;
    size_t totf4 = (size_t)N * 8;
#pragma unroll
    for (int i = 0; i < 2; i++) {
        int idx = t + i * 256;
        size_t gidx = (size_t)r0 * 8 + idx;
        Xs4[idx] = (gidx < totf4) ? xg[idx] : make_float4(0.f, 0.f, 0.f, 0.f);
    }
    __syncthreads();
    float ps = 0.f, pq = 0.f;
    for (int rr = sub; rr < 64; rr += 4) {
        int r = r0 + rr;
        if (r >= N) break;
        float acc = b;
        const float4* a4p = (const float4*)(Xs + rr * 32);
#pragma unroll
        for (int kk = 0; kk < 8; kk++) {
            float4 a4 = a4p[kk];
            acc += a4.x * w[kk * 4] + a4.y * w[kk * 4 + 1] + a4.z * w[kk * 4 + 2] + a4.w * w[kk * 4 + 3];
        }
        float hv = fmaxf(acc, 0.f);
        h16[(size_t)r * 64 + col] = (_Float16)hv;
        ps += hv; pq += hv * hv;
    }
    ls[t] = ps; lq[t] = pq;
    __syncthreads();
    if (t < 64) {
        bnpart[(size_t)blockIdx.x * 128 + t] = ls[t] + ls[t + 64] + ls[t + 128] + ls[t + 192];
        bnpart[(size_t)blockIdx.x * 128 + 64 + t] = lq[t] + lq[t + 64] + lq[t + 128] + lq[t + 192];
    }
}

// reduce bnpart over blocks: red[stat] = sum_b bnpart[b][stat], stat = blockIdx (128 blocks)
__global__ void bn_reduce_kernel(const float* __restrict__ bnpart, int nb, float* __restrict__ red) {
    __shared__ float s[256];
    int stat = blockIdx.x;
    float acc = 0.f;
    for (int j = threadIdx.x; j < nb; j += 256) acc += bnpart[(size_t)j * 128 + stat];
    s[threadIdx.x] = acc;
    __syncthreads();
    for (int off = 128; off >= 1; off >>= 1) {
        if (threadIdx.x < off) s[threadIdx.x] += s[threadIdx.x + off];
        __syncthreads();
    }
    if (threadIdx.x == 0) red[stat] = s[0];
}

// ============================ fold (parallel) ============================
__global__ void fold2_kernel(const float* __restrict__ red,
                             const float* __restrict__ gamma, const float* __restrict__ beta,
                             const float* __restrict__ convw,
                             const float* __restrict__ atts, const float* __restrict__ attd,
                             _Float16* __restrict__ Wt, float* __restrict__ bpb,
                             float* __restrict__ P, float* __restrict__ cs,
                             float invN) {
    __shared__ float scl[64], sft[64], bs[256];
    int t = threadIdx.x;
    if (t < 64) {
        float mu = red[t] * invN;
        float var = fmaxf(red[64 + t] * invN - mu * mu, 0.f);
        float sc = gamma[t] / sqrtf(var + EPS_BN);
        scl[t] = sc;
        sft[t] = beta[t] - mu * sc;
    }
    __syncthreads();
    int b = blockIdx.x;
    if (b < 64) {
        int col = b;
        int c = t >> 2, hh = t & 3;
        Wt[col * 256 + t] = (_Float16)(0.25f * scl[c] * convw[c * 256 + hh * 64 + col]);
    } else if (b == 64) {
        for (int idx = t; idx < 512; idx += 256) {
            int k = idx >> 3, o = idx & 7, hh = o & 3;
            const float* av = (o < 4) ? atts : attd;
            float acc = 0.f;
            for (int c2 = 0; c2 < 64; c2++) acc += convw[k * 256 + hh * 64 + c2] * av[hh * 64 + c2];
            P[idx] = scl[k] * acc;
        }
    } else {
        float bacc = 0.f;
        for (int k = 0; k < 64; k++) bacc += sft[k] * convw[k * 256 + t];
        bpb[t] = bacc;
        bs[t] = bacc;
        __syncthreads();
        if (t < 8) {
            int hh = t & 3;
            const float* av = (t < 4) ? atts : attd;
            float acc = 0.f;
            for (int c2 = 0; c2 < 64; c2++) acc += bs[hh * 64 + c2] * av[hh * 64 + c2];
            cs[t] = acc;
        }
    }
}

// ============================ per-node attention logits: a_sd = h16 @ P + cs ============================
__global__ void att_node_kernel(const _Float16* __restrict__ h16, const float* __restrict__ P,
                                const float* __restrict__ cs, float* __restrict__ a_sd, int N) {
    __shared__ float As[32 * 68];
    __shared__ float Ps[512];
    __shared__ float css[8];
    int t = threadIdx.x;
    int r0 = blockIdx.x * 32;
    const f16x8* hg = (const f16x8*)(h16 + (size_t)r0 * 64);
    size_t tot8 = (size_t)N * 8;
    {
        int row = t >> 3, ch8 = (t & 7) * 8;
        size_t g8 = (size_t)r0 * 8 + t;
        f16x8 v = {};
        if (g8 < tot8) v = hg[t];
#pragma unroll
        for (int k = 0; k < 8; k++) As[row * 68 + ch8 + k] = (float)v[k];
    }
    Ps[t] = P[t];
    Ps[t + 256] = P[t + 256];
    if (t < 8) css[t] = cs[t];
    __syncthreads();
    int row = t >> 3, o = t & 7;
    int rg = r0 + row;
    if (rg >= N) return;
    float a0 = 0.f, a1 = 0.f, a2 = 0.f, a3 = 0.f;
#pragma unroll
    for (int k = 0; k < 16; k++) {
        a0 += As[row * 68 + 4 * k + 0] * Ps[(4 * k + 0) * 8 + o];
        a1 += As[row * 68 + 4 * k + 1] * Ps[(4 * k + 1) * 8 + o];
        a2 += As[row * 68 + 4 * k + 2] * Ps[(4 * k + 2) * 8 + o];
        a3 += As[row * 68 + 4 * k + 3] * Ps[(4 * k + 3) * 8 + o];
    }
    a_sd[(size_t)rg * 8 + o] = css[o] + (a0 + a1) + (a2 + a3);
}

// ============================ fused scores + aggregation + projection (MFMA) ============================
// 32-node tile per block, 4 waves; slot = 16 lanes owns TWO nodes (rows wv*8+slot, +4),
// edge chunks interleaved -> 8 independent gather chains/wave. Per 4-edge chunk: one int4
// src load, 4 independent 8B f16 h-row gathers, per-lane score+exp, 16 shuffles broadcast,
// fp16 packed accumulation (v_pk_fma_f16, channel-major). MFMA projects two 16-row tiles.
__global__ __launch_bounds__(256) void msg_proj_kernel(
        const int* __restrict__ row_ptr, const int* __restrict__ src_csr,
        const _Float16* __restrict__ ae_l, const float* __restrict__ a_sd,
        const _Float16* __restrict__ h16_in,
        const _Float16* __restrict__ Wt, const float* __restrict__ bpb,
        const float* __restrict__ bias,
        _Float16* __restrict__ h16_out, float* __restrict__ bnpart, int N) {
    __shared__ __attribute__((aligned(16))) _Float16 Aagg[32][264];
    __shared__ __attribute__((aligned(16))) float sals[32][4];
    int t = threadIdx.x;
    int wv = t >> 6, lane = t & 63;
    int colg = wv * 16 + (lane & 15);
    int kb = (lane >> 4) * 8;
    int slot = lane >> 4, c4 = lane & 15;
    int head = c4 & 3, j = c4 >> 2;
    int sb_ = lane & 48;   // slot base lane in wave
    int nb0 = blockIdx.x * 32;
    int rows[2] = {wv * 8 + slot, wv * 8 + slot + 4};

    float bpbc[4];
#pragma unroll
    for (int hh = 0; hh < 4; hh++) bpbc[hh] = bpb[hh * 64 + colg] * 0.25f;
    float bcol = bias[colg];

    h2 Acc[2][4][2];    // [node][head][channel-pair], fp16 packed
    float dd[2][4];
    int p1v[2];
    float adv[2];
    int base0, base1;
#pragma unroll
    for (int u = 0; u < 2; u++) {
#pragma unroll
        for (int h = 0; h < 4; h++) {
            Acc[u][h][0] = (h2){(_Float16)0.f, (_Float16)0.f};
            Acc[u][h][1] = (h2){(_Float16)0.f, (_Float16)0.f};
            dd[u][h] = 0.f;
        }
        int n = nb0 + rows[u];
        int p0 = 0, p1 = 0;
        if (n < N) { p0 = row_ptr[n]; p1 = row_ptr[n + 1]; }
        adv[u] = (p0 < p1) ? a_sd[(size_t)n * 8 + 4 + head] : 0.f;
        p1v[u] = p1;
        if (u == 0) base0 = p0; else base1 = p0;
    }

    auto chunk = [&](int u, int base) {
        int rem = p1v[u] - base;
        int4u sv = *(const int4u*)(src_csr + base);
        int sa = sv.x;
        int sbv = rem > 1 ? sv.y : sa;
        int scv = rem > 2 ? sv.z : sbv;
        int sdv = rem > 3 ? sv.w : scv;
        int jj = j < rem ? j : rem - 1;
        int mysrc = j == 0 ? sa : (j == 1 ? sbv : (j == 2 ? scv : sdv));
        float myas = a_sd[(size_t)mysrc * 8 + head];
        float aev = (float)ae_l[(size_t)(base + jj) * 4 + head];
        union H4 { f16x4 v; h2 p[2]; } ua, ub, uc, ud;
        ua.v = *(const f16x4*)(h16_in + ((size_t)sa << 6) + (c4 << 2));
        ub.v = *(const f16x4*)(h16_in + ((size_t)sbv << 6) + (c4 << 2));
        uc.v = *(const f16x4*)(h16_in + ((size_t)scv << 6) + (c4 << 2));
        ud.v = *(const f16x4*)(h16_in + ((size_t)sdv << 6) + (c4 << 2));
        float s = myas + adv[u] + aev;
        s = s > 0.f ? s : 0.2f * s;
        float ex = (j < rem) ? __expf(s) : 0.f;
        float ea0 = __shfl(ex, sb_ + 0), ea1 = __shfl(ex, sb_ + 1);
        float ea2 = __shfl(ex, sb_ + 2), ea3 = __shfl(ex, sb_ + 3);
        float eb0 = __shfl(ex, sb_ + 4), eb1 = __shfl(ex, sb_ + 5);
        float eb2 = __shfl(ex, sb_ + 6), eb3 = __shfl(ex, sb_ + 7);
        float ec0 = __shfl(ex, sb_ + 8), ec1 = __shfl(ex, sb_ + 9);
        float ec2 = __shfl(ex, sb_ + 10), ec3 = __shfl(ex, sb_ + 11);
        float ed0 = __shfl(ex, sb_ + 12), ed1 = __shfl(ex, sb_ + 13);
        float ed2 = __shfl(ex, sb_ + 14), ed3 = __shfl(ex, sb_ + 15);
        dd[u][0] += (ea0 + eb0) + (ec0 + ed0);
        dd[u][1] += (ea1 + eb1) + (ec1 + ed1);
        dd[u][2] += (ea2 + eb2) + (ec2 + ed2);
        dd[u][3] += (ea3 + eb3) + (ec3 + ed3);
#define ACC_ROW(HU, E0, E1, E2, E3)                                           \
        {                                                                     \
            _Float16 w0 = (_Float16)(E0), w1 = (_Float16)(E1);                \
            _Float16 w2 = (_Float16)(E2), w3 = (_Float16)(E3);                \
            h2 W0 = {w0, w0}, W1 = {w1, w1}, W2 = {w2, w2}, W3 = {w3, w3};    \
            Acc[u][0][0] += W0 * HU.p[0]; Acc[u][0][1] += W0 * HU.p[1];       \
            Acc[u][1][0] += W1 * HU.p[0]; Acc[u][1][1] += W1 * HU.p[1];       \
            Acc[u][2][0] += W2 * HU.p[0]; Acc[u][2][1] += W2 * HU.p[1];       \
            Acc[u][3][0] += W3 * HU.p[0]; Acc[u][3][1] += W3 * HU.p[1];       \
        }
        ACC_ROW(ua, ea0, ea1, ea2, ea3)
        ACC_ROW(ub, eb0, eb1, eb2, eb3)
        ACC_ROW(uc, ec0, ec1, ec2, ec3)
        ACC_ROW(ud, ed0, ed1, ed2, ed3)
#undef ACC_ROW
    };

    while (base0 < p1v[0] || base1 < p1v[1]) {
        if (base0 < p1v[0]) chunk(0, base0);
        if (base1 < p1v[1]) chunk(1, base1);
        base0 += 4; base1 += 4;
    }

#pragma unroll
    for (int u = 0; u < 2; u++) {
        f16x8 v0, v1;
#pragma unroll
        for (int h = 0; h < 4; h++) {
            float d = dd[u][h];
            float invd = d > 0.f ? 1.f / (d + EPS_SM) : 0.f;
            _Float16 ih = (_Float16)invd;
            h2 IH = {ih, ih};
            h2 q0 = Acc[u][h][0] * IH;
            h2 q1 = Acc[u][h][1] * IH;
            v0[h] = q0.x; v0[4 + h] = q0.y;
            v1[h] = q1.x; v1[4 + h] = q1.y;
        }
        *(f16x8*)&Aagg[rows[u]][c4 * 16] = v0;
        *(f16x8*)&Aagg[rows[u]][c4 * 16 + 8] = v1;
        if (c4 == 0) {
            float4 sv2;
            sv2.x = dd[u][0] / (dd[u][0] + EPS_SM);
            sv2.y = dd[u][1] / (dd[u][1] + EPS_SM);
            sv2.z = dd[u][2] / (dd[u][2] + EPS_SM);
            sv2.w = dd[u][3] / (dd[u][3] + EPS_SM);
            *(float4*)&sals[rows[u]][0] = sv2;
        }
    }
    // B fragments loaded here (overlaps LDS drain before the barrier)
    f16x8 bfrag[8];
    const _Float16* wtp = Wt + (size_t)colg * 256 + kb;
#pragma unroll
    for (int ks = 0; ks < 8; ks++) bfrag[ks] = *(const f16x8*)(wtp + ks * 32);
    __syncthreads();

    // -------- MFMA phase: two 16-row tiles --------
    float ps = 0.f, pq = 0.f;
#pragma unroll
    for (int half = 0; half < 2; half++) {
        f32x4 acc = {0.f, 0.f, 0.f, 0.f};
        const _Float16* ap = &Aagg[half * 16 + (lane & 15)][kb];
#pragma unroll
        for (int ks = 0; ks < 8; ks++) {
            f16x8 af = *(const f16x8*)(ap + ks * 32);
            acc = __builtin_amdgcn_mfma_f32_16x16x32_f16(af, bfrag[ks], acc, 0, 0, 0);
        }
        int r0 = half * 16 + (lane >> 4) * 4;
#pragma unroll
        for (int reg = 0; reg < 4; reg++) {
            int rr = r0 + reg;
            int nn = nb0 + rr;
            if (nn < N) {
                float v = acc[reg] + sals[rr][0] * bpbc[0] + sals[rr][1] * bpbc[1]
                        + sals[rr][2] * bpbc[2] + sals[rr][3] * bpbc[3] + bcol;
                size_t idx = ((size_t)nn << 6) + colg;
                float hv = (float)h16_in[idx];
                float outv = fmaxf(v, 0.f) + hv;
                h16_out[idx] = (_Float16)outv;
                ps += outv;
                pq += outv * outv;
            }
        }
    }
    // reduce the 4 row-quads (lanes differing in bits 4,5) -> per-col BN partials
    ps += __shfl_xor(ps, 16); ps += __shfl_xor(ps, 32);
    pq += __shfl_xor(pq, 16); pq += __shfl_xor(pq, 32);
    if ((lane >> 4) == 0) {
        bnpart[(size_t)blockIdx.x * 128 + colg] = ps;
        bnpart[(size_t)blockIdx.x * 128 + 64 + colg] = pq;
    }
}

// ============================ pooling + FC head ============================
__global__ void pool_fc_kernel(const _Float16* __restrict__ h16, const int* __restrict__ gptr,
                               const float* __restrict__ fc1_w, const float* __restrict__ fc1_b,
                               const float* __restrict__ fc2_w, const float* __restrict__ fc2_b,
                               float* __restrict__ out, int G) {
    __shared__ float pool[4][64];
    int lane = threadIdx.x & 63, wv = threadIdx.x >> 6;
    int g = blockIdx.x * 4 + wv;
    float acc = 0.f;
    if (g < G) {
        int a = gptr[g], b = gptr[g + 1];
        for (int r = a; r < b; r++) acc += (float)h16[(size_t)r * 64 + lane];
    }
    pool[wv][lane] = acc;
    __syncthreads();
    float z1 = fc1_b[lane];
#pragma unroll 8
    for (int c = 0; c < 64; c++) z1 += pool[wv][c] * fc1_w[c * 64 + lane];
    z1 = fmaxf(z1, 0.f);
    float z2 = z1 * fc2_w[lane];
    z2 += __shfl_xor(z2, 1);
    z2 += __shfl_xor(z2, 2);
    z2 += __shfl_xor(z2, 4);
    z2 += __shfl_xor(z2, 8);
    z2 += __shfl_xor(z2, 16);
    z2 += __shfl_xor(z2, 32);
    if (g < G && lane == 0) out[g] = fmaxf(z2 + fc2_b[0], 0.f);
}

// ============================ host ============================
extern "C" void kernel_launch(void* const* d_in, const int* in_sizes, int n_in,
                              void* d_out, int out_size, void* d_ws, size_t ws_size,
                              hipStream_t stream) {
    const float* x         = (const float*)d_in[0];
    const int*   eindex    = (const int*)d_in[1];
    const float* edge_attr = (const float*)d_in[2];
    const int*   batch     = (const int*)d_in[3];
    const float* lin_w     = (const float*)d_in[4];
    const float* lin_b     = (const float*)d_in[5];
    const float* bn_gamma  = (const float*)d_in[6];
    const float* bn_beta   = (const float*)d_in[7];
    const float* conv_w    = (const float*)d_in[8];
    const float* conv_we   = (const float*)d_in[9];
    const float* att_src   = (const float*)d_in[10];
    const float* att_dst   = (const float*)d_in[11];
    const float* att_edge  = (const float*)d_in[12];
    const float* conv_bias = (const float*)d_in[13];
    const float* fc1_w     = (const float*)d_in[14];
    const float* fc1_b     = (const float*)d_in[15];
    const float* fc2_w     = (const float*)d_in[16];
    const float* fc2_b     = (const float*)d_in[17];
    float* out = (float*)d_out;

    int N = in_sizes[3];
    int E = in_sizes[1] / 2;
    int G = out_size;
    const int* esrc = eindex;
    const int* edst = eindex + E;

    char* wp = (char*)d_ws;
    auto carve = [&](size_t b) -> char* {
        char* p = wp;
        wp += (b + 511) & ~(size_t)511;
        return p;
    };
    _Float16*  h16b0  = (_Float16*)carve((size_t)N * 64 * 2);     // 25.6 MB
    _Float16*  h16b1  = (_Float16*)carve((size_t)N * 64 * 2);     // 25.6 MB
    float*     a_sd   = (float*)carve((size_t)N * 8 * 4);         //  6.4 MB
    _Float16*  ae_csr = (_Float16*)carve((size_t)3 * E * 4 * 2);  //  9.6 MB
    int*       src_csr= (int*)carve((size_t)(E + 4) * 4);         //  1.6 MB (+pad for int4 tail)
    int*       deg    = (int*)carve((size_t)N * 4);
    int*       row_ptr= (int*)carve((size_t)(N + 1) * 4);
    int*       cursor = (int*)carve((size_t)N * 4);
    int*       bsum   = (int*)carve(4096);
    int*       gptr   = (int*)carve((size_t)(G + 1) * 4);
    float*     bpb    = (float*)carve(256 * 4);
    float*     P      = (float*)carve(512 * 4);
    float*     cs     = (float*)carve(8 * 4);
    float*     Qm3    = (float*)carve(96 * 4);
    _Float16*  Wt     = (_Float16*)carve(64 * 256 * 2);
    float*     red    = (float*)carve(128 * 4);
    int nb1 = (N + 255) / 256;
    int nbP = (N + 63) / 64;
    int nTiles = (N + 31) / 32;
    int maxPart = nbP > nTiles ? nbP : nTiles;
    float*     bnpart = (float*)carve((size_t)maxPart * 128 * 4);

    // merged setup (zero deg | Qm3 | gptr), then CSR + scatter
    int gBlocks = (G + 1 + 255) / 256;
    setup_kernel<<<nb1 + 1 + gBlocks, 256, 0, stream>>>(deg, N, nb1, conv_we, att_edge, Qm3,
                                                        batch, gptr, G);
    hist_kernel<<<(E + 255) / 256, 256, 0, stream>>>(edst, deg, E);
    scan1_kernel<<<nb1, 256, 0, stream>>>(deg, row_ptr, bsum, N);
    scan2_kernel<<<1, 1024, 0, stream>>>(bsum, nb1);
    scan3_kernel<<<(N + 1 + 255) / 256, 256, 0, stream>>>(row_ptr, cursor, bsum, N, E);
    scatter_kernel<<<(E + 255) / 256, 256, 0, stream>>>(esrc, edst, edge_attr, Qm3,
                                                        cursor, src_csr, ae_csr, E);

    // input projection (+ BN partials for layer 0)
    proj_kernel<<<nbP, 256, 0, stream>>>(x, lin_w, lin_b, h16b0, bnpart, N);

    int cur = 0;
    _Float16* h16buf[2] = {h16b0, h16b1};
    int nbPart = nbP;   // partial count for current layer's BN

    for (int l = 0; l < 3; l++) {
        _Float16* h16c = h16buf[cur];
        _Float16* h16n = h16buf[cur ^ 1];
        bn_reduce_kernel<<<128, 256, 0, stream>>>(bnpart, nbPart, red);
        fold2_kernel<<<66, 256, 0, stream>>>(red,
                                             bn_gamma + l * 64, bn_beta + l * 64,
                                             conv_w + (size_t)l * 64 * 256,
                                             att_src + l * 256, att_dst + l * 256,
                                             Wt, bpb, P, cs, 1.f / (float)N);
        att_node_kernel<<<(N + 31) / 32, 256, 0, stream>>>(h16c, P, cs, a_sd, N);
        msg_proj_kernel<<<nTiles, 256, 0, stream>>>(row_ptr, src_csr,
                                                    ae_csr + (size_t)l * E * 4, a_sd,
                                                    h16c, Wt, bpb, conv_bias + l * 64,
                                                    h16n, bnpart, N);
        nbPart = nTiles;
        cur ^= 1;
    }

    pool_fc_kernel<<<(G + 3) / 4, 256, 0, stream>>>(h16buf[cur], gptr, fc1_w, fc1_b, fc2_w, fc2_b,
                                                    out, G);
}

// Round 12
// 503.030 us; speedup vs baseline: 1.2595x; 1.0129x over previous
//
#include <hip/hip_runtime.h>
#include <cmath>

#define EPS_BN 1e-5f
#define EPS_SM 1e-16f

typedef _Float16 f16x8 __attribute__((ext_vector_type(8)));
typedef _Float16 f16x4 __attribute__((ext_vector_type(4)));
typedef _Float16 h2 __attribute__((ext_vector_type(2)));
typedef float f32x4 __attribute__((ext_vector_type(4)));
typedef int int2a __attribute__((ext_vector_type(2), aligned(4)));
union F4 { float4 v; float a[4]; };

// ============================ CSR build ============================
__global__ void hist_kernel(const int* __restrict__ edst, int* __restrict__ deg, int E) {
    int e = blockIdx.x * 256 + threadIdx.x;
    if (e < E) atomicAdd(&deg[edst[e]], 1);
}

__global__ void scan1_kernel(const int* __restrict__ deg, int* __restrict__ row_ptr,
                             int* __restrict__ bsum, int N) {
    __shared__ int s[256];
    int t = threadIdx.x;
    int i = blockIdx.x * 256 + t;
    int v = (i < N) ? deg[i] : 0;
    s[t] = v; __syncthreads();
    for (int off = 1; off < 256; off <<= 1) {
        int x = (t >= off) ? s[t - off] : 0;
        __syncthreads();
        s[t] += x;
        __syncthreads();
    }
    if (i < N) row_ptr[i] = s[t] - v;   // exclusive partial
    if (t == 255) bsum[blockIdx.x] = s[t];
}

__global__ void scan2_kernel(int* __restrict__ bsum, int nb) {
    __shared__ int s[1024];
    int t = threadIdx.x;
    int v = (t < nb) ? bsum[t] : 0;
    s[t] = v; __syncthreads();
    for (int off = 1; off < 1024; off <<= 1) {
        int x = (t >= off) ? s[t - off] : 0;
        __syncthreads();
        s[t] += x;
        __syncthreads();
    }
    if (t < nb) bsum[t] = s[t] - v;     // exclusive
}

__global__ void scan3_kernel(int* __restrict__ row_ptr, int* __restrict__ cursor,
                             const int* __restrict__ bsum, int N, int E) {
    int i = blockIdx.x * 256 + threadIdx.x;
    if (i < N) {
        int v = row_ptr[i] + bsum[blockIdx.x];
        row_ptr[i] = v;
        cursor[i] = v;
    } else if (i == N) {
        row_ptr[N] = E;
    }
}

// ============================ merged setup: zero deg | Qm3 | gptr ============================
__global__ void setup_kernel(int* __restrict__ deg, int N, int nb1,
                             const float* __restrict__ convwe, const float* __restrict__ atte,
                             float* __restrict__ Qm3,
                             const int* __restrict__ batch, int* __restrict__ gptr, int G) {
    int b = blockIdx.x;
    int t = threadIdx.x;
    if (b < nb1) {
        int i = b * 256 + t;
        if (i < N) deg[i] = 0;
    } else if (b == nb1) {
        if (t >= 96) return;
        int l = t >> 5, f = (t >> 2) & 7, hh = t & 3;
        const float* we = convwe + (size_t)l * 8 * 256;
        const float* av = atte + (size_t)l * 256;
        float acc = 0.f;
        for (int c = 0; c < 64; c++) acc += we[f * 256 + hh * 64 + c] * av[hh * 64 + c];
        Qm3[t] = acc;
    } else {
        int g = (b - nb1 - 1) * 256 + t;
        if (g > G) return;
        int lo = 0, hi = N;
        while (lo < hi) { int mid = (lo + hi) >> 1; if (batch[mid] < g) lo = mid + 1; else hi = mid; }
        gptr[g] = lo;
    }
}

// scatter edges to CSR order: src_csr[p] = src, ae_csr[l][p][4] = f16(edge_attr@Qm3[l])
__global__ void scatter_kernel(const int* __restrict__ esrc, const int* __restrict__ edst,
                               const float* __restrict__ edge_attr, const float* __restrict__ Qm3,
                               int* __restrict__ cursor, int* __restrict__ src_csr,
                               _Float16* __restrict__ ae_csr, int E) {
    __shared__ float q[96];
    int t = threadIdx.x;
    if (t < 96) q[t] = Qm3[t];
    __syncthreads();
    int e = blockIdx.x * 256 + t;
    if (e >= E) return;
    int src = esrc[e];
    int p = atomicAdd(&cursor[edst[e]], 1);
    src_csr[p] = src;
    F4 ea0, ea1;
    ea0.v = ((const float4*)edge_attr)[(size_t)e * 2];
    ea1.v = ((const float4*)edge_attr)[(size_t)e * 2 + 1];
#pragma unroll
    for (int l = 0; l < 3; l++) {
        const float* ql = q + l * 32;
        f16x4 r;
#pragma unroll
        for (int hh = 0; hh < 4; hh++) {
            float acc = ea0.a[0] * ql[0 * 4 + hh] + ea0.a[1] * ql[1 * 4 + hh]
                      + ea0.a[2] * ql[2 * 4 + hh] + ea0.a[3] * ql[3 * 4 + hh]
                      + ea1.a[0] * ql[4 * 4 + hh] + ea1.a[1] * ql[5 * 4 + hh]
                      + ea1.a[2] * ql[6 * 4 + hh] + ea1.a[3] * ql[7 * 4 + hh];
            r[hh] = (_Float16)acc;
        }
        *(f16x4*)(ae_csr + ((size_t)l * E + p) * 4) = r;
    }
}

// ============================ input projection (h16 + BN partials) ============================
__global__ void proj_kernel(const float* __restrict__ x, const float* __restrict__ lin_w,
                            const float* __restrict__ lin_b,
                            _Float16* __restrict__ h16, float* __restrict__ bnpart, int N) {
    __shared__ float Xs[64 * 32];
    __shared__ float ls[256], lq[256];
    int t = threadIdx.x;
    int col = t & 63, sub = t >> 6;
    float w[32];
#pragma unroll
    for (int k = 0; k < 32; k++) w[k] = lin_w[k * 64 + col];
    float b = lin_b[col];
    int r0 = blockIdx.x * 64;
    const float4* xg = (const float4*)(x + (size_t)r0 * 32);
    float4* Xs4 = (float4*)Xs;
    size_t totf4 = (size_t)N * 8;
#pragma unroll
    for (int i = 0; i < 2; i++) {
        int idx = t + i * 256;
        size_t gidx = (size_t)r0 * 8 + idx;
        Xs4[idx] = (gidx < totf4) ? xg[idx] : make_float4(0.f, 0.f, 0.f, 0.f);
    }
    __syncthreads();
    float ps = 0.f, pq = 0.f;
    for (int rr = sub; rr < 64; rr += 4) {
        int r = r0 + rr;
        if (r >= N) break;
        float acc = b;
        const float4* a4p = (const float4*)(Xs + rr * 32);
#pragma unroll
        for (int kk = 0; kk < 8; kk++) {
            float4 a4 = a4p[kk];
            acc += a4.x * w[kk * 4] + a4.y * w[kk * 4 + 1] + a4.z * w[kk * 4 + 2] + a4.w * w[kk * 4 + 3];
        }
        float hv = fmaxf(acc, 0.f);
        h16[(size_t)r * 64 + col] = (_Float16)hv;
        ps += hv; pq += hv * hv;
    }
    ls[t] = ps; lq[t] = pq;
    __syncthreads();
    if (t < 64) {
        bnpart[(size_t)blockIdx.x * 128 + t] = ls[t] + ls[t + 64] + ls[t + 128] + ls[t + 192];
        bnpart[(size_t)blockIdx.x * 128 + 64 + t] = lq[t] + lq[t + 64] + lq[t + 128] + lq[t + 192];
    }
}

// reduce bnpart over blocks: red[stat] = sum_b bnpart[b][stat], stat = blockIdx (128 blocks)
__global__ void bn_reduce_kernel(const float* __restrict__ bnpart, int nb, float* __restrict__ red) {
    __shared__ float s[256];
    int stat = blockIdx.x;
    float acc = 0.f;
    for (int j = threadIdx.x; j < nb; j += 256) acc += bnpart[(size_t)j * 128 + stat];
    s[threadIdx.x] = acc;
    __syncthreads();
    for (int off = 128; off >= 1; off >>= 1) {
        if (threadIdx.x < off) s[threadIdx.x] += s[threadIdx.x + off];
        __syncthreads();
    }
    if (threadIdx.x == 0) red[stat] = s[0];
}

// ============================ fold (parallel) ============================
__global__ void fold2_kernel(const float* __restrict__ red,
                             const float* __restrict__ gamma, const float* __restrict__ beta,
                             const float* __restrict__ convw,
                             const float* __restrict__ atts, const float* __restrict__ attd,
                             _Float16* __restrict__ Wt, float* __restrict__ bpb,
                             float* __restrict__ P, float* __restrict__ cs,
                             float invN) {
    __shared__ float scl[64], sft[64], bs[256];
    int t = threadIdx.x;
    if (t < 64) {
        float mu = red[t] * invN;
        float var = fmaxf(red[64 + t] * invN - mu * mu, 0.f);
        float sc = gamma[t] / sqrtf(var + EPS_BN);
        scl[t] = sc;
        sft[t] = beta[t] - mu * sc;
    }
    __syncthreads();
    int b = blockIdx.x;
    if (b < 64) {
        int col = b;
        int c = t >> 2, hh = t & 3;
        Wt[col * 256 + t] = (_Float16)(0.25f * scl[c] * convw[c * 256 + hh * 64 + col]);
    } else if (b == 64) {
        for (int idx = t; idx < 512; idx += 256) {
            int k = idx >> 3, o = idx & 7, hh = o & 3;
            const float* av = (o < 4) ? atts : attd;
            float acc = 0.f;
            for (int c2 = 0; c2 < 64; c2++) acc += convw[k * 256 + hh * 64 + c2] * av[hh * 64 + c2];
            P[idx] = scl[k] * acc;
        }
    } else {
        float bacc = 0.f;
        for (int k = 0; k < 64; k++) bacc += sft[k] * convw[k * 256 + t];
        bpb[t] = bacc;
        bs[t] = bacc;
        __syncthreads();
        if (t < 8) {
            int hh = t & 3;
            const float* av = (t < 4) ? atts : attd;
            float acc = 0.f;
            for (int c2 = 0; c2 < 64; c2++) acc += bs[hh * 64 + c2] * av[hh * 64 + c2];
            cs[t] = acc;
        }
    }
}

// ============================ per-node attention logits: a_sd = f16(h16 @ P + cs) ============================
__global__ void att_node_kernel(const _Float16* __restrict__ h16, const float* __restrict__ P,
                                const float* __restrict__ cs, _Float16* __restrict__ a_sd, int N) {
    __shared__ float As[32 * 68];
    __shared__ float Ps[512];
    __shared__ float css[8];
    int t = threadIdx.x;
    int r0 = blockIdx.x * 32;
    const f16x8* hg = (const f16x8*)(h16 + (size_t)r0 * 64);
    size_t tot8 = (size_t)N * 8;
    {
        int row = t >> 3, ch8 = (t & 7) * 8;
        size_t g8 = (size_t)r0 * 8 + t;
        f16x8 v = {};
        if (g8 < tot8) v = hg[t];
#pragma unroll
        for (int k = 0; k < 8; k++) As[row * 68 + ch8 + k] = (float)v[k];
    }
    Ps[t] = P[t];
    Ps[t + 256] = P[t + 256];
    if (t < 8) css[t] = cs[t];
    __syncthreads();
    int row = t >> 3, o = t & 7;
    int rg = r0 + row;
    if (rg >= N) return;
    float a0 = 0.f, a1 = 0.f, a2 = 0.f, a3 = 0.f;
#pragma unroll
    for (int k = 0; k < 16; k++) {
        a0 += As[row * 68 + 4 * k + 0] * Ps[(4 * k + 0) * 8 + o];
        a1 += As[row * 68 + 4 * k + 1] * Ps[(4 * k + 1) * 8 + o];
        a2 += As[row * 68 + 4 * k + 2] * Ps[(4 * k + 2) * 8 + o];
        a3 += As[row * 68 + 4 * k + 3] * Ps[(4 * k + 3) * 8 + o];
    }
    a_sd[(size_t)rg * 8 + o] = (_Float16)(css[o] + (a0 + a1) + (a2 + a3));
}

// ============================ fused scores + aggregation + projection (MFMA) ============================
// 32-node tile per block, 4 waves; slot = 16 lanes owns TWO nodes (rows wv*8+slot, +4),
// edge chunks interleaved -> 4 independent gather chains/wave-slot-pair. 2-EDGE chunks
// (deg ~ Poisson(2): ~40% of 4-edge chunk work was clamped waste): one int2 src load,
// 2 independent 8B f16 h-row gathers, scoring on lanes j<2, 8 shuffles, 16 pk_fma.
// MFMA projects two 16-row tiles. Epilogue: skip-add, h16 write, BN partials.
__global__ __launch_bounds__(256) void msg_proj_kernel(
        const int* __restrict__ row_ptr, const int* __restrict__ src_csr,
        const _Float16* __restrict__ ae_l, const _Float16* __restrict__ a_sd,
        const _Float16* __restrict__ h16_in,
        const _Float16* __restrict__ Wt, const float* __restrict__ bpb,
        const float* __restrict__ bias,
        _Float16* __restrict__ h16_out, float* __restrict__ bnpart, int N) {
    __shared__ __attribute__((aligned(16))) _Float16 Aagg[32][264];
    __shared__ __attribute__((aligned(16))) float sals[32][4];
    int t = threadIdx.x;
    int wv = t >> 6, lane = t & 63;
    int colg = wv * 16 + (lane & 15);
    int kb = (lane >> 4) * 8;
    int slot = lane >> 4, c4 = lane & 15;
    int head = c4 & 3, j = c4 >> 2;
    int sb_ = lane & 48;   // slot base lane in wave
    int nb0 = blockIdx.x * 32;
    int rows[2] = {wv * 8 + slot, wv * 8 + slot + 4};

    float bpbc[4];
#pragma unroll
    for (int hh = 0; hh < 4; hh++) bpbc[hh] = bpb[hh * 64 + colg] * 0.25f;
    float bcol = bias[colg];

    h2 Acc[2][4][2];    // [node][head][channel-pair], fp16 packed
    float dd[2][4];
    int p1v[2];
    float adv[2];
    int base0, base1;
#pragma unroll
    for (int u = 0; u < 2; u++) {
#pragma unroll
        for (int h = 0; h < 4; h++) {
            Acc[u][h][0] = (h2){(_Float16)0.f, (_Float16)0.f};
            Acc[u][h][1] = (h2){(_Float16)0.f, (_Float16)0.f};
            dd[u][h] = 0.f;
        }
        int n = nb0 + rows[u];
        int p0 = 0, p1 = 0;
        if (n < N) { p0 = row_ptr[n]; p1 = row_ptr[n + 1]; }
        adv[u] = (p0 < p1) ? (float)a_sd[(size_t)n * 8 + 4 + head] : 0.f;
        p1v[u] = p1;
        if (u == 0) base0 = p0; else base1 = p0;
    }

    auto chunk = [&](int u, int base) {
        int rem = p1v[u] - base;
        int2a sv = *(const int2a*)(src_csr + base);
        int sa = sv.x;
        int sbv = rem > 1 ? sv.y : sa;
        int mysrc = (j == 1) ? sbv : sa;
        float myas = (float)a_sd[(size_t)mysrc * 8 + head];
        int jc = (j == 1 && rem > 1) ? 1 : 0;
        float aev = (float)ae_l[(size_t)(base + jc) * 4 + head];
        union H4 { f16x4 v; h2 p[2]; } ua, ub;
        ua.v = *(const f16x4*)(h16_in + ((size_t)sa << 6) + (c4 << 2));
        ub.v = *(const f16x4*)(h16_in + ((size_t)sbv << 6) + (c4 << 2));
        float s = myas + adv[u] + aev;
        s = s > 0.f ? s : 0.2f * s;
        float ex = (j < 2 && j < rem) ? __expf(s) : 0.f;
        float ea0 = __shfl(ex, sb_ + 0), ea1 = __shfl(ex, sb_ + 1);
        float ea2 = __shfl(ex, sb_ + 2), ea3 = __shfl(ex, sb_ + 3);
        float eb0 = __shfl(ex, sb_ + 4), eb1 = __shfl(ex, sb_ + 5);
        float eb2 = __shfl(ex, sb_ + 6), eb3 = __shfl(ex, sb_ + 7);
        dd[u][0] += ea0 + eb0;
        dd[u][1] += ea1 + eb1;
        dd[u][2] += ea2 + eb2;
        dd[u][3] += ea3 + eb3;
#define ACC_ROW(HU, E0, E1, E2, E3)                                           \
        {                                                                     \
            _Float16 w0 = (_Float16)(E0), w1 = (_Float16)(E1);                \
            _Float16 w2 = (_Float16)(E2), w3 = (_Float16)(E3);                \
            h2 W0 = {w0, w0}, W1 = {w1, w1}, W2 = {w2, w2}, W3 = {w3, w3};    \
            Acc[u][0][0] += W0 * HU.p[0]; Acc[u][0][1] += W0 * HU.p[1];       \
            Acc[u][1][0] += W1 * HU.p[0]; Acc[u][1][1] += W1 * HU.p[1];       \
            Acc[u][2][0] += W2 * HU.p[0]; Acc[u][2][1] += W2 * HU.p[1];       \
            Acc[u][3][0] += W3 * HU.p[0]; Acc[u][3][1] += W3 * HU.p[1];       \
        }
        ACC_ROW(ua, ea0, ea1, ea2, ea3)
        ACC_ROW(ub, eb0, eb1, eb2, eb3)
#undef ACC_ROW
    };

    while (base0 < p1v[0] || base1 < p1v[1]) {
        if (base0 < p1v[0]) chunk(0, base0);
        if (base1 < p1v[1]) chunk(1, base1);
        base0 += 2; base1 += 2;
    }

#pragma unroll
    for (int u = 0; u < 2; u++) {
        f16x8 v0, v1;
#pragma unroll
        for (int h = 0; h < 4; h++) {
            float d = dd[u][h];
            float invd = d > 0.f ? 1.f / (d + EPS_SM) : 0.f;
            _Float16 ih = (_Float16)invd;
            h2 IH = {ih, ih};
            h2 q0 = Acc[u][h][0] * IH;
            h2 q1 = Acc[u][h][1] * IH;
            v0[h] = q0.x; v0[4 + h] = q0.y;
            v1[h] = q1.x; v1[4 + h] = q1.y;
        }
        *(f16x8*)&Aagg[rows[u]][c4 * 16] = v0;
        *(f16x8*)&Aagg[rows[u]][c4 * 16 + 8] = v1;
        if (c4 == 0) {
            float4 sv2;
            sv2.x = dd[u][0] / (dd[u][0] + EPS_SM);
            sv2.y = dd[u][1] / (dd[u][1] + EPS_SM);
            sv2.z = dd[u][2] / (dd[u][2] + EPS_SM);
            sv2.w = dd[u][3] / (dd[u][3] + EPS_SM);
            *(float4*)&sals[rows[u]][0] = sv2;
        }
    }
    // B fragments loaded here (overlaps LDS drain before the barrier)
    f16x8 bfrag[8];
    const _Float16* wtp = Wt + (size_t)colg * 256 + kb;
#pragma unroll
    for (int ks = 0; ks < 8; ks++) bfrag[ks] = *(const f16x8*)(wtp + ks * 32);
    __syncthreads();

    // -------- MFMA phase: two 16-row tiles --------
    float ps = 0.f, pq = 0.f;
#pragma unroll
    for (int half = 0; half < 2; half++) {
        f32x4 acc = {0.f, 0.f, 0.f, 0.f};
        const _Float16* ap = &Aagg[half * 16 + (lane & 15)][kb];
#pragma unroll
        for (int ks = 0; ks < 8; ks++) {
            f16x8 af = *(const f16x8*)(ap + ks * 32);
            acc = __builtin_amdgcn_mfma_f32_16x16x32_f16(af, bfrag[ks], acc, 0, 0, 0);
        }
        int r0 = half * 16 + (lane >> 4) * 4;
#pragma unroll
        for (int reg = 0; reg < 4; reg++) {
            int rr = r0 + reg;
            int nn = nb0 + rr;
            if (nn < N) {
                float v = acc[reg] + sals[rr][0] * bpbc[0] + sals[rr][1] * bpbc[1]
                        + sals[rr][2] * bpbc[2] + sals[rr][3] * bpbc[3] + bcol;
                size_t idx = ((size_t)nn << 6) + colg;
                float hv = (float)h16_in[idx];
                float outv = fmaxf(v, 0.f) + hv;
                h16_out[idx] = (_Float16)outv;
                ps += outv;
                pq += outv * outv;
            }
        }
    }
    // reduce the 4 row-quads (lanes differing in bits 4,5) -> per-col BN partials
    ps += __shfl_xor(ps, 16); ps += __shfl_xor(ps, 32);
    pq += __shfl_xor(pq, 16); pq += __shfl_xor(pq, 32);
    if ((lane >> 4) == 0) {
        bnpart[(size_t)blockIdx.x * 128 + colg] = ps;
        bnpart[(size_t)blockIdx.x * 128 + 64 + colg] = pq;
    }
}

// ============================ pooling + FC head ============================
__global__ void pool_fc_kernel(const _Float16* __restrict__ h16, const int* __restrict__ gptr,
                               const float* __restrict__ fc1_w, const float* __restrict__ fc1_b,
                               const float* __restrict__ fc2_w, const float* __restrict__ fc2_b,
                               float* __restrict__ out, int G) {
    __shared__ float pool[4][64];
    int lane = threadIdx.x & 63, wv = threadIdx.x >> 6;
    int g = blockIdx.x * 4 + wv;
    float acc = 0.f;
    if (g < G) {
        int a = gptr[g], b = gptr[g + 1];
        for (int r = a; r < b; r++) acc += (float)h16[(size_t)r * 64 + lane];
    }
    pool[wv][lane] = acc;
    __syncthreads();
    float z1 = fc1_b[lane];
#pragma unroll 8
    for (int c = 0; c < 64; c++) z1 += pool[wv][c] * fc1_w[c * 64 + lane];
    z1 = fmaxf(z1, 0.f);
    float z2 = z1 * fc2_w[lane];
    z2 += __shfl_xor(z2, 1);
    z2 += __shfl_xor(z2, 2);
    z2 += __shfl_xor(z2, 4);
    z2 += __shfl_xor(z2, 8);
    z2 += __shfl_xor(z2, 16);
    z2 += __shfl_xor(z2, 32);
    if (g < G && lane == 0) out[g] = fmaxf(z2 + fc2_b[0], 0.f);
}

// ============================ host ============================
extern "C" void kernel_launch(void* const* d_in, const int* in_sizes, int n_in,
                              void* d_out, int out_size, void* d_ws, size_t ws_size,
                              hipStream_t stream) {
    const float* x         = (const float*)d_in[0];
    const int*   eindex    = (const int*)d_in[1];
    const float* edge_attr = (const float*)d_in[2];
    const int*   batch     = (const int*)d_in[3];
    const float* lin_w     = (const float*)d_in[4];
    const float* lin_b     = (const float*)d_in[5];
    const float* bn_gamma  = (const float*)d_in[6];
    const float* bn_beta   = (const float*)d_in[7];
    const float* conv_w    = (const float*)d_in[8];
    const float* conv_we   = (const float*)d_in[9];
    const float* att_src   = (const float*)d_in[10];
    const float* att_dst   = (const float*)d_in[11];
    const float* att_edge  = (const float*)d_in[12];
    const float* conv_bias = (const float*)d_in[13];
    const float* fc1_w     = (const float*)d_in[14];
    const float* fc1_b     = (const float*)d_in[15];
    const float* fc2_w     = (const float*)d_in[16];
    const float* fc2_b     = (const float*)d_in[17];
    float* out = (float*)d_out;

    int N = in_sizes[3];
    int E = in_sizes[1] / 2;
    int G = out_size;
    const int* esrc = eindex;
    const int* edst = eindex + E;

    char* wp = (char*)d_ws;
    auto carve = [&](size_t b) -> char* {
        char* p = wp;
        wp += (b + 511) & ~(size_t)511;
        return p;
    };
    _Float16*  h16b0  = (_Float16*)carve((size_t)N * 64 * 2);     // 25.6 MB
    _Float16*  h16b1  = (_Float16*)carve((size_t)N * 64 * 2);     // 25.6 MB
    _Float16*  a_sd   = (_Float16*)carve((size_t)N * 8 * 2);      //  3.2 MB
    _Float16*  ae_csr = (_Float16*)carve((size_t)3 * E * 4 * 2);  //  9.6 MB
    int*       src_csr= (int*)carve((size_t)(E + 4) * 4);         //  1.6 MB (+pad for tail)
    int*       deg    = (int*)carve((size_t)N * 4);
    int*       row_ptr= (int*)carve((size_t)(N + 1) * 4);
    int*       cursor = (int*)carve((size_t)N * 4);
    int*       bsum   = (int*)carve(4096);
    int*       gptr   = (int*)carve((size_t)(G + 1) * 4);
    float*     bpb    = (float*)carve(256 * 4);
    float*     P      = (float*)carve(512 * 4);
    float*     cs     = (float*)carve(8 * 4);
    float*     Qm3    = (float*)carve(96 * 4);
    _Float16*  Wt     = (_Float16*)carve(64 * 256 * 2);
    float*     red    = (float*)carve(128 * 4);
    int nb1 = (N + 255) / 256;
    int nbP = (N + 63) / 64;
    int nTiles = (N + 31) / 32;
    int maxPart = nbP > nTiles ? nbP : nTiles;
    float*     bnpart = (float*)carve((size_t)maxPart * 128 * 4);

    // merged setup (zero deg | Qm3 | gptr), then CSR + scatter
    int gBlocks = (G + 1 + 255) / 256;
    setup_kernel<<<nb1 + 1 + gBlocks, 256, 0, stream>>>(deg, N, nb1, conv_we, att_edge, Qm3,
                                                        batch, gptr, G);
    hist_kernel<<<(E + 255) / 256, 256, 0, stream>>>(edst, deg, E);
    scan1_kernel<<<nb1, 256, 0, stream>>>(deg, row_ptr, bsum, N);
    scan2_kernel<<<1, 1024, 0, stream>>>(bsum, nb1);
    scan3_kernel<<<(N + 1 + 255) / 256, 256, 0, stream>>>(row_ptr, cursor, bsum, N, E);
    scatter_kernel<<<(E + 255) / 256, 256, 0, stream>>>(esrc, edst, edge_attr, Qm3,
                                                        cursor, src_csr, ae_csr, E);

    // input projection (+ BN partials for layer 0)
    proj_kernel<<<nbP, 256, 0, stream>>>(x, lin_w, lin_b, h16b0, bnpart, N);

    int cur = 0;
    _Float16* h16buf[2] = {h16b0, h16b1};
    int nbPart = nbP;   // partial count for current layer's BN

    for (int l = 0; l < 3; l++) {
        _Float16* h16c = h16buf[cur];
        _Float16* h16n = h16buf[cur ^ 1];
        bn_reduce_kernel<<<128, 256, 0, stream>>>(bnpart, nbPart, red);
        fold2_kernel<<<66, 256, 0, stream>>>(red,
                                             bn_gamma + l * 64, bn_beta + l * 64,
                                             conv_w + (size_t)l * 64 * 256,
                                             att_src + l * 256, att_dst + l * 256,
                                             Wt, bpb, P, cs, 1.f / (float)N);
        att_node_kernel<<<(N + 31) / 32, 256, 0, stream>>>(h16c, P, cs, a_sd, N);
        msg_proj_kernel<<<nTiles, 256, 0, stream>>>(row_ptr, src_csr,
                                                    ae_csr + (size_t)l * E * 4, a_sd,
                                                    h16c, Wt, bpb, conv_bias + l * 64,
                                                    h16n, bnpart, N);
        nbPart = nTiles;
        cur ^= 1;
    }

    pool_fc_kernel<<<(G + 3) / 4, 256, 0, stream>>>(h16buf[cur], gptr, fc1_w, fc1_b, fc2_w, fc2_b,
                                                    out, G);
}

// Round 13
// 499.721 us; speedup vs baseline: 1.2678x; 1.0066x over previous
//
#include <hip/hip_runtime.h>
#include <cmath>

#define EPS_BN 1e-5f
#define EPS_SM 1e-16f

typedef _Float16 f16x8 __attribute__((ext_vector_type(8)));
typedef _Float16 f16x4 __attribute__((ext_vector_type(4)));
typedef _Float16 h2 __attribute__((ext_vector_type(2)));
typedef float f32x4 __attribute__((ext_vector_type(4)));
typedef int int2a __attribute__((ext_vector_type(2), aligned(4)));
union F4 { float4 v; float a[4]; };

// ============================ CSR build ============================
__global__ void hist_kernel(const int* __restrict__ edst, int* __restrict__ deg, int E) {
    int e = blockIdx.x * 256 + threadIdx.x;
    if (e < E) atomicAdd(&deg[edst[e]], 1);
}

__global__ void scan1_kernel(const int* __restrict__ deg, int* __restrict__ row_ptr,
                             int* __restrict__ bsum, int N) {
    __shared__ int s[256];
    int t = threadIdx.x;
    int i = blockIdx.x * 256 + t;
    int v = (i < N) ? deg[i] : 0;
    s[t] = v; __syncthreads();
    for (int off = 1; off < 256; off <<= 1) {
        int x = (t >= off) ? s[t - off] : 0;
        __syncthreads();
        s[t] += x;
        __syncthreads();
    }
    if (i < N) row_ptr[i] = s[t] - v;   // exclusive partial
    if (t == 255) bsum[blockIdx.x] = s[t];
}

__global__ void scan2_kernel(int* __restrict__ bsum, int nb) {
    __shared__ int s[1024];
    int t = threadIdx.x;
    int v = (t < nb) ? bsum[t] : 0;
    s[t] = v; __syncthreads();
    for (int off = 1; off < 1024; off <<= 1) {
        int x = (t >= off) ? s[t - off] : 0;
        __syncthreads();
        s[t] += x;
        __syncthreads();
    }
    if (t < nb) bsum[t] = s[t] - v;     // exclusive
}

__global__ void scan3_kernel(int* __restrict__ row_ptr, int* __restrict__ cursor,
                             const int* __restrict__ bsum, int N, int E) {
    int i = blockIdx.x * 256 + threadIdx.x;
    if (i < N) {
        int v = row_ptr[i] + bsum[blockIdx.x];
        row_ptr[i] = v;
        cursor[i] = v;
    } else if (i == N) {
        row_ptr[N] = E;
    }
}

// ============================ merged setup: zero deg | Qm3 | gptr ============================
__global__ void setup_kernel(int* __restrict__ deg, int N, int nb1,
                             const float* __restrict__ convwe, const float* __restrict__ atte,
                             float* __restrict__ Qm3,
                             const int* __restrict__ batch, int* __restrict__ gptr, int G) {
    int b = blockIdx.x;
    int t = threadIdx.x;
    if (b < nb1) {
        int i = b * 256 + t;
        if (i < N) deg[i] = 0;
    } else if (b == nb1) {
        if (t >= 96) return;
        int l = t >> 5, f = (t >> 2) & 7, hh = t & 3;
        const float* we = convwe + (size_t)l * 8 * 256;
        const float* av = atte + (size_t)l * 256;
        float acc = 0.f;
        for (int c = 0; c < 64; c++) acc += we[f * 256 + hh * 64 + c] * av[hh * 64 + c];
        Qm3[t] = acc;
    } else {
        int g = (b - nb1 - 1) * 256 + t;
        if (g > G) return;
        int lo = 0, hi = N;
        while (lo < hi) { int mid = (lo + hi) >> 1; if (batch[mid] < g) lo = mid + 1; else hi = mid; }
        gptr[g] = lo;
    }
}

// scatter edges to CSR order: src_csr[p] = src, ae_csr[l][p][4] = f16(edge_attr@Qm3[l])
__global__ void scatter_kernel(const int* __restrict__ esrc, const int* __restrict__ edst,
                               const float* __restrict__ edge_attr, const float* __restrict__ Qm3,
                               int* __restrict__ cursor, int* __restrict__ src_csr,
                               _Float16* __restrict__ ae_csr, int E) {
    __shared__ float q[96];
    int t = threadIdx.x;
    if (t < 96) q[t] = Qm3[t];
    __syncthreads();
    int e = blockIdx.x * 256 + t;
    if (e >= E) return;
    int src = esrc[e];
    int p = atomicAdd(&cursor[edst[e]], 1);
    src_csr[p] = src;
    F4 ea0, ea1;
    ea0.v = ((const float4*)edge_attr)[(size_t)e * 2];
    ea1.v = ((const float4*)edge_attr)[(size_t)e * 2 + 1];
#pragma unroll
    for (int l = 0; l < 3; l++) {
        const float* ql = q + l * 32;
        f16x4 r;
#pragma unroll
        for (int hh = 0; hh < 4; hh++) {
            float acc = ea0.a[0] * ql[0 * 4 + hh] + ea0.a[1] * ql[1 * 4 + hh]
                      + ea0.a[2] * ql[2 * 4 + hh] + ea0.a[3] * ql[3 * 4 + hh]
                      + ea1.a[0] * ql[4 * 4 + hh] + ea1.a[1] * ql[5 * 4 + hh]
                      + ea1.a[2] * ql[6 * 4 + hh] + ea1.a[3] * ql[7 * 4 + hh];
            r[hh] = (_Float16)acc;
        }
        *(f16x4*)(ae_csr + ((size_t)l * E + p) * 4) = r;
    }
}

// ============================ input projection (h16 + BN partials) ============================
__global__ void proj_kernel(const float* __restrict__ x, const float* __restrict__ lin_w,
                            const float* __restrict__ lin_b,
                            _Float16* __restrict__ h16, float* __restrict__ bnpart, int N) {
    __shared__ float Xs[64 * 32];
    __shared__ float ls[256], lq[256];
    int t = threadIdx.x;
    int col = t & 63, sub = t >> 6;
    float w[32];
#pragma unroll
    for (int k = 0; k < 32; k++) w[k] = lin_w[k * 64 + col];
    float b = lin_b[col];
    int r0 = blockIdx.x * 64;
    const float4* xg = (const float4*)(x + (size_t)r0 * 32);
    float4* Xs4 = (float4*)Xs;
    size_t totf4 = (size_t)N * 8;
#pragma unroll
    for (int i = 0; i < 2; i++) {
        int idx = t + i * 256;
        size_t gidx = (size_t)r0 * 8 + idx;
        Xs4[idx] = (gidx < totf4) ? xg[idx] : make_float4(0.f, 0.f, 0.f, 0.f);
    }
    __syncthreads();
    float ps = 0.f, pq = 0.f;
    for (int rr = sub; rr < 64; rr += 4) {
        int r = r0 + rr;
        if (r >= N) break;
        float acc = b;
        const float4* a4p = (const float4*)(Xs + rr * 32);
#pragma unroll
        for (int kk = 0; kk < 8; kk++) {
            float4 a4 = a4p[kk];
            acc += a4.x * w[kk * 4] + a4.y * w[kk * 4 + 1] + a4.z * w[kk * 4 + 2] + a4.w * w[kk * 4 + 3];
        }
        float hv = fmaxf(acc, 0.f);
        h16[(size_t)r * 64 + col] = (_Float16)hv;
        ps += hv; pq += hv * hv;
    }
    ls[t] = ps; lq[t] = pq;
    __syncthreads();
    if (t < 64) {
        bnpart[(size_t)blockIdx.x * 128 + t] = ls[t] + ls[t + 64] + ls[t + 128] + ls[t + 192];
        bnpart[(size_t)blockIdx.x * 128 + 64 + t] = lq[t] + lq[t + 64] + lq[t + 128] + lq[t + 192];
    }
}

// reduce bnpart over blocks: red[stat] = sum_b bnpart[b][stat], stat = blockIdx (128 blocks)
__global__ void bn_reduce_kernel(const float* __restrict__ bnpart, int nb, float* __restrict__ red) {
    __shared__ float s[256];
    int stat = blockIdx.x;
    float acc = 0.f;
    for (int j = threadIdx.x; j < nb; j += 256) acc += bnpart[(size_t)j * 128 + stat];
    s[threadIdx.x] = acc;
    __syncthreads();
    for (int off = 128; off >= 1; off >>= 1) {
        if (threadIdx.x < off) s[threadIdx.x] += s[threadIdx.x + off];
        __syncthreads();
    }
    if (threadIdx.x == 0) red[stat] = s[0];
}

// ============================ fold (parallel) ============================
// blocks 0..63 : Wt[col=b][k=t] = 0.25*scl[k>>2]*convw[(k>>2)*256 + (k&3)*64 + col]
// block 64     : Pt[o][k] f16 = scl[k]*dot(convw[k][hh*64..], att{s|d}[hh]); rows 8..15 = 0
// block 65     : bpb[t] = sum_k sft[k]*convw[k][t];  then cs[8]
__global__ void fold2_kernel(const float* __restrict__ red,
                             const float* __restrict__ gamma, const float* __restrict__ beta,
                             const float* __restrict__ convw,
                             const float* __restrict__ atts, const float* __restrict__ attd,
                             _Float16* __restrict__ Wt, float* __restrict__ bpb,
                             _Float16* __restrict__ Pt, float* __restrict__ cs,
                             float invN) {
    __shared__ float scl[64], sft[64], bs[256];
    int t = threadIdx.x;
    if (t < 64) {
        float mu = red[t] * invN;
        float var = fmaxf(red[64 + t] * invN - mu * mu, 0.f);
        float sc = gamma[t] / sqrtf(var + EPS_BN);
        scl[t] = sc;
        sft[t] = beta[t] - mu * sc;
    }
    __syncthreads();
    int b = blockIdx.x;
    if (b < 64) {
        int col = b;
        int c = t >> 2, hh = t & 3;
        Wt[col * 256 + t] = (_Float16)(0.25f * scl[c] * convw[c * 256 + hh * 64 + col]);
    } else if (b == 64) {
        for (int idx = t; idx < 512; idx += 256) {
            int k = idx >> 3, o = idx & 7, hh = o & 3;
            const float* av = (o < 4) ? atts : attd;
            float acc = 0.f;
            for (int c2 = 0; c2 < 64; c2++) acc += convw[k * 256 + hh * 64 + c2] * av[hh * 64 + c2];
            Pt[o * 64 + k] = (_Float16)(scl[k] * acc);
        }
        for (int idx = t; idx < 512; idx += 256) Pt[512 + idx] = (_Float16)0.f;
    } else {
        float bacc = 0.f;
        for (int k = 0; k < 64; k++) bacc += sft[k] * convw[k * 256 + t];
        bpb[t] = bacc;
        bs[t] = bacc;
        __syncthreads();
        if (t < 8) {
            int hh = t & 3;
            const float* av = (t < 4) ? atts : attd;
            float acc = 0.f;
            for (int c2 = 0; c2 < 64; c2++) acc += bs[hh * 64 + c2] * av[hh * 64 + c2];
            cs[t] = acc;
        }
    }
}

// ============================ per-node attention logits via MFMA ============================
// a_sd[64x8 per block] = h16[64x64] @ Pt^T  (+cs). 4 waves x 16 rows; two 16x16x32 MFMAs
// per wave (K=64). A loaded directly from h16 in fragment layout; B from Pt[16][64] f16.
__global__ __launch_bounds__(256) void att_node_kernel(
        const _Float16* __restrict__ h16, const _Float16* __restrict__ Pt,
        const float* __restrict__ cs, _Float16* __restrict__ a_sd, int N) {
    int t = threadIdx.x;
    int wv = t >> 6, lane = t & 63;
    int m = lane & 15, quad = lane >> 4, kb = quad * 8;
    int r0 = blockIdx.x * 64 + wv * 16;
    f16x8 b0 = *(const f16x8*)(Pt + m * 64 + kb);
    f16x8 b1 = *(const f16x8*)(Pt + m * 64 + 32 + kb);
    f16x8 a0 = {}, a1 = {};
    int rm = r0 + m;
    if (rm < N) {
        a0 = *(const f16x8*)(h16 + ((size_t)rm << 6) + kb);
        a1 = *(const f16x8*)(h16 + ((size_t)rm << 6) + 32 + kb);
    }
    f32x4 acc = {0.f, 0.f, 0.f, 0.f};
    acc = __builtin_amdgcn_mfma_f32_16x16x32_f16(a0, b0, acc, 0, 0, 0);
    acc = __builtin_amdgcn_mfma_f32_16x16x32_f16(a1, b1, acc, 0, 0, 0);
    if (m < 8) {
        float cso = cs[m];
#pragma unroll
        for (int reg = 0; reg < 4; reg++) {
            int rg = r0 + quad * 4 + reg;
            if (rg < N) a_sd[(size_t)rg * 8 + m] = (_Float16)(acc[reg] + cso);
        }
    }
}

// ============================ fused scores + aggregation + projection (MFMA) ============================
// 64-node tile per block, 4 waves; slot = 16 lanes owns FOUR nodes (rows wv*16+slot+{0,4,8,12}),
// edge chunks interleaved -> 8 independent gather chains per slot-pair. 2-edge chunks:
// one int2 src load, 2 independent 8B f16 h-row gathers, scoring on lanes j<2, 8 shuffles,
// 16 pk_fma (fp16 packed, channel-major). MFMA projects four 16-row tiles.
__global__ __launch_bounds__(256) void msg_proj_kernel(
        const int* __restrict__ row_ptr, const int* __restrict__ src_csr,
        const _Float16* __restrict__ ae_l, const _Float16* __restrict__ a_sd,
        const _Float16* __restrict__ h16_in,
        const _Float16* __restrict__ Wt, const float* __restrict__ bpb,
        const float* __restrict__ bias,
        _Float16* __restrict__ h16_out, float* __restrict__ bnpart, int N) {
    __shared__ __attribute__((aligned(16))) _Float16 Aagg[64][264];
    __shared__ __attribute__((aligned(16))) float sals[64][4];
    int t = threadIdx.x;
    int wv = t >> 6, lane = t & 63;
    int colg = wv * 16 + (lane & 15);
    int kb = (lane >> 4) * 8;
    int slot = lane >> 4, c4 = lane & 15;
    int head = c4 & 3, j = c4 >> 2;
    int sb_ = lane & 48;   // slot base lane in wave
    int nb0 = blockIdx.x * 64;

    float bpbc[4];
#pragma unroll
    for (int hh = 0; hh < 4; hh++) bpbc[hh] = bpb[hh * 64 + colg] * 0.25f;
    float bcol = bias[colg];

    h2 Acc[4][4][2];    // [node][head][channel-pair], fp16 packed
    float dd[4][4];
    int p1v[4], bases[4], rows[4];
    float adv[4];
#pragma unroll
    for (int u = 0; u < 4; u++) {
        rows[u] = wv * 16 + slot + u * 4;
#pragma unroll
        for (int h = 0; h < 4; h++) {
            Acc[u][h][0] = (h2){(_Float16)0.f, (_Float16)0.f};
            Acc[u][h][1] = (h2){(_Float16)0.f, (_Float16)0.f};
            dd[u][h] = 0.f;
        }
        int n = nb0 + rows[u];
        int p0 = 0, p1 = 0;
        if (n < N) { p0 = row_ptr[n]; p1 = row_ptr[n + 1]; }
        adv[u] = (p0 < p1) ? (float)a_sd[(size_t)n * 8 + 4 + head] : 0.f;
        p1v[u] = p1;
        bases[u] = p0;
    }

    auto chunk = [&](int u, int base) {
        int rem = p1v[u] - base;
        int2a sv = *(const int2a*)(src_csr + base);
        int sa = sv.x;
        int sbv = rem > 1 ? sv.y : sa;
        int mysrc = (j == 1) ? sbv : sa;
        float myas = (float)a_sd[(size_t)mysrc * 8 + head];
        int jc = (j == 1 && rem > 1) ? 1 : 0;
        float aev = (float)ae_l[(size_t)(base + jc) * 4 + head];
        union H4 { f16x4 v; h2 p[2]; } ua, ub;
        ua.v = *(const f16x4*)(h16_in + ((size_t)sa << 6) + (c4 << 2));
        ub.v = *(const f16x4*)(h16_in + ((size_t)sbv << 6) + (c4 << 2));
        float s = myas + adv[u] + aev;
        s = s > 0.f ? s : 0.2f * s;
        float ex = (j < 2 && j < rem) ? __expf(s) : 0.f;
        float ea0 = __shfl(ex, sb_ + 0), ea1 = __shfl(ex, sb_ + 1);
        float ea2 = __shfl(ex, sb_ + 2), ea3 = __shfl(ex, sb_ + 3);
        float eb0 = __shfl(ex, sb_ + 4), eb1 = __shfl(ex, sb_ + 5);
        float eb2 = __shfl(ex, sb_ + 6), eb3 = __shfl(ex, sb_ + 7);
        dd[u][0] += ea0 + eb0;
        dd[u][1] += ea1 + eb1;
        dd[u][2] += ea2 + eb2;
        dd[u][3] += ea3 + eb3;
#define ACC_ROW(HU, E0, E1, E2, E3)                                           \
        {                                                                     \
            _Float16 w0 = (_Float16)(E0), w1 = (_Float16)(E1);                \
            _Float16 w2 = (_Float16)(E2), w3 = (_Float16)(E3);                \
            h2 W0 = {w0, w0}, W1 = {w1, w1}, W2 = {w2, w2}, W3 = {w3, w3};    \
            Acc[u][0][0] += W0 * HU.p[0]; Acc[u][0][1] += W0 * HU.p[1];       \
            Acc[u][1][0] += W1 * HU.p[0]; Acc[u][1][1] += W1 * HU.p[1];       \
            Acc[u][2][0] += W2 * HU.p[0]; Acc[u][2][1] += W2 * HU.p[1];       \
            Acc[u][3][0] += W3 * HU.p[0]; Acc[u][3][1] += W3 * HU.p[1];       \
        }
        ACC_ROW(ua, ea0, ea1, ea2, ea3)
        ACC_ROW(ub, eb0, eb1, eb2, eb3)
#undef ACC_ROW
    };

    while (bases[0] < p1v[0] || bases[1] < p1v[1] || bases[2] < p1v[2] || bases[3] < p1v[3]) {
#pragma unroll
        for (int u = 0; u < 4; u++) {
            if (bases[u] < p1v[u]) { chunk(u, bases[u]); bases[u] += 2; }
        }
    }

#pragma unroll
    for (int u = 0; u < 4; u++) {
        f16x8 v0, v1;
#pragma unroll
        for (int h = 0; h < 4; h++) {
            float d = dd[u][h];
            float invd = d > 0.f ? 1.f / (d + EPS_SM) : 0.f;
            _Float16 ih = (_Float16)invd;
            h2 IH = {ih, ih};
            h2 q0 = Acc[u][h][0] * IH;
            h2 q1 = Acc[u][h][1] * IH;
            v0[h] = q0.x; v0[4 + h] = q0.y;
            v1[h] = q1.x; v1[4 + h] = q1.y;
        }
        *(f16x8*)&Aagg[rows[u]][c4 * 16] = v0;
        *(f16x8*)&Aagg[rows[u]][c4 * 16 + 8] = v1;
        if (c4 == 0) {
            float4 sv2;
            sv2.x = dd[u][0] / (dd[u][0] + EPS_SM);
            sv2.y = dd[u][1] / (dd[u][1] + EPS_SM);
            sv2.z = dd[u][2] / (dd[u][2] + EPS_SM);
            sv2.w = dd[u][3] / (dd[u][3] + EPS_SM);
            *(float4*)&sals[rows[u]][0] = sv2;
        }
    }
    // B fragments loaded here (overlaps LDS drain before the barrier)
    f16x8 bfrag[8];
    const _Float16* wtp = Wt + (size_t)colg * 256 + kb;
#pragma unroll
    for (int ks = 0; ks < 8; ks++) bfrag[ks] = *(const f16x8*)(wtp + ks * 32);
    __syncthreads();

    // -------- MFMA phase: four 16-row tiles --------
    float ps = 0.f, pq = 0.f;
#pragma unroll
    for (int half = 0; half < 4; half++) {
        f32x4 acc = {0.f, 0.f, 0.f, 0.f};
        const _Float16* ap = &Aagg[half * 16 + (lane & 15)][kb];
#pragma unroll
        for (int ks = 0; ks < 8; ks++) {
            f16x8 af = *(const f16x8*)(ap + ks * 32);
            acc = __builtin_amdgcn_mfma_f32_16x16x32_f16(af, bfrag[ks], acc, 0, 0, 0);
        }
        int r0 = half * 16 + (lane >> 4) * 4;
#pragma unroll
        for (int reg = 0; reg < 4; reg++) {
            int rr = r0 + reg;
            int nn = nb0 + rr;
            if (nn < N) {
                float v = acc[reg] + sals[rr][0] * bpbc[0] + sals[rr][1] * bpbc[1]
                        + sals[rr][2] * bpbc[2] + sals[rr][3] * bpbc[3] + bcol;
                size_t idx = ((size_t)nn << 6) + colg;
                float hv = (float)h16_in[idx];
                float outv = fmaxf(v, 0.f) + hv;
                h16_out[idx] = (_Float16)outv;
                ps += outv;
                pq += outv * outv;
            }
        }
    }
    // reduce the 4 row-quads (lanes differing in bits 4,5) -> per-col BN partials
    ps += __shfl_xor(ps, 16); ps += __shfl_xor(ps, 32);
    pq += __shfl_xor(pq, 16); pq += __shfl_xor(pq, 32);
    if ((lane >> 4) == 0) {
        bnpart[(size_t)blockIdx.x * 128 + colg] = ps;
        bnpart[(size_t)blockIdx.x * 128 + 64 + colg] = pq;
    }
}

// ============================ pooling + FC head ============================
__global__ void pool_fc_kernel(const _Float16* __restrict__ h16, const int* __restrict__ gptr,
                               const float* __restrict__ fc1_w, const float* __restrict__ fc1_b,
                               const float* __restrict__ fc2_w, const float* __restrict__ fc2_b,
                               float* __restrict__ out, int G) {
    __shared__ float pool[4][64];
    int lane = threadIdx.x & 63, wv = threadIdx.x >> 6;
    int g = blockIdx.x * 4 + wv;
    float acc = 0.f;
    if (g < G) {
        int a = gptr[g], b = gptr[g + 1];
        for (int r = a; r < b; r++) acc += (float)h16[(size_t)r * 64 + lane];
    }
    pool[wv][lane] = acc;
    __syncthreads();
    float z1 = fc1_b[lane];
#pragma unroll 8
    for (int c = 0; c < 64; c++) z1 += pool[wv][c] * fc1_w[c * 64 + lane];
    z1 = fmaxf(z1, 0.f);
    float z2 = z1 * fc2_w[lane];
    z2 += __shfl_xor(z2, 1);
    z2 += __shfl_xor(z2, 2);
    z2 += __shfl_xor(z2, 4);
    z2 += __shfl_xor(z2, 8);
    z2 += __shfl_xor(z2, 16);
    z2 += __shfl_xor(z2, 32);
    if (g < G && lane == 0) out[g] = fmaxf(z2 + fc2_b[0], 0.f);
}

// ============================ host ============================
extern "C" void kernel_launch(void* const* d_in, const int* in_sizes, int n_in,
                              void* d_out, int out_size, void* d_ws, size_t ws_size,
                              hipStream_t stream) {
    const float* x         = (const float*)d_in[0];
    const int*   eindex    = (const int*)d_in[1];
    const float* edge_attr = (const float*)d_in[2];
    const int*   batch     = (const int*)d_in[3];
    const float* lin_w     = (const float*)d_in[4];
    const float* lin_b     = (const float*)d_in[5];
    const float* bn_gamma  = (const float*)d_in[6];
    const float* bn_beta   = (const float*)d_in[7];
    const float* conv_w    = (const float*)d_in[8];
    const float* conv_we   = (const float*)d_in[9];
    const float* att_src   = (const float*)d_in[10];
    const float* att_dst   = (const float*)d_in[11];
    const float* att_edge  = (const float*)d_in[12];
    const float* conv_bias = (const float*)d_in[13];
    const float* fc1_w     = (const float*)d_in[14];
    const float* fc1_b     = (const float*)d_in[15];
    const float* fc2_w     = (const float*)d_in[16];
    const float* fc2_b     = (const float*)d_in[17];
    float* out = (float*)d_out;

    int N = in_sizes[3];
    int E = in_sizes[1] / 2;
    int G = out_size;
    const int* esrc = eindex;
    const int* edst = eindex + E;

    char* wp = (char*)d_ws;
    auto carve = [&](size_t b) -> char* {
        char* p = wp;
        wp += (b + 511) & ~(size_t)511;
        return p;
    };
    _Float16*  h16b0  = (_Float16*)carve((size_t)N * 64 * 2);     // 25.6 MB
    _Float16*  h16b1  = (_Float16*)carve((size_t)N * 64 * 2);     // 25.6 MB
    _Float16*  a_sd   = (_Float16*)carve((size_t)N * 8 * 2);      //  3.2 MB
    _Float16*  ae_csr = (_Float16*)carve((size_t)3 * E * 4 * 2);  //  9.6 MB
    int*       src_csr= (int*)carve((size_t)(E + 4) * 4);         //  1.6 MB (+pad for tail)
    int*       deg    = (int*)carve((size_t)N * 4);
    int*       row_ptr= (int*)carve((size_t)(N + 1) * 4);
    int*       cursor = (int*)carve((size_t)N * 4);
    int*       bsum   = (int*)carve(4096);
    int*       gptr   = (int*)carve((size_t)(G + 1) * 4);
    float*     bpb    = (float*)carve(256 * 4);
    _Float16*  Pt     = (_Float16*)carve(1024 * 2);
    float*     cs     = (float*)carve(8 * 4);
    float*     Qm3    = (float*)carve(96 * 4);
    _Float16*  Wt     = (_Float16*)carve(64 * 256 * 2);
    float*     red    = (float*)carve(128 * 4);
    int nb1 = (N + 255) / 256;
    int nbP = (N + 63) / 64;
    int nT64 = (N + 63) / 64;
    int maxPart = nbP > nT64 ? nbP : nT64;
    float*     bnpart = (float*)carve((size_t)maxPart * 128 * 4);

    // merged setup (zero deg | Qm3 | gptr), then CSR + scatter
    int gBlocks = (G + 1 + 255) / 256;
    setup_kernel<<<nb1 + 1 + gBlocks, 256, 0, stream>>>(deg, N, nb1, conv_we, att_edge, Qm3,
                                                        batch, gptr, G);
    hist_kernel<<<(E + 255) / 256, 256, 0, stream>>>(edst, deg, E);
    scan1_kernel<<<nb1, 256, 0, stream>>>(deg, row_ptr, bsum, N);
    scan2_kernel<<<1, 1024, 0, stream>>>(bsum, nb1);
    scan3_kernel<<<(N + 1 + 255) / 256, 256, 0, stream>>>(row_ptr, cursor, bsum, N, E);
    scatter_kernel<<<(E + 255) / 256, 256, 0, stream>>>(esrc, edst, edge_attr, Qm3,
                                                        cursor, src_csr, ae_csr, E);

    // input projection (+ BN partials for layer 0)
    proj_kernel<<<nbP, 256, 0, stream>>>(x, lin_w, lin_b, h16b0, bnpart, N);

    int cur = 0;
    _Float16* h16buf[2] = {h16b0, h16b1};
    int nbPart = nbP;   // partial count for current layer's BN

    for (int l = 0; l < 3; l++) {
        _Float16* h16c = h16buf[cur];
        _Float16* h16n = h16buf[cur ^ 1];
        bn_reduce_kernel<<<128, 256, 0, stream>>>(bnpart, nbPart, red);
        fold2_kernel<<<66, 256, 0, stream>>>(red,
                                             bn_gamma + l * 64, bn_beta + l * 64,
                                             conv_w + (size_t)l * 64 * 256,
                                             att_src + l * 256, att_dst + l * 256,
                                             Wt, bpb, Pt, cs, 1.f / (float)N);
        att_node_kernel<<<(N + 63) / 64, 256, 0, stream>>>(h16c, Pt, cs, a_sd, N);
        msg_proj_kernel<<<nT64, 256, 0, stream>>>(row_ptr, src_csr,
                                                  ae_csr + (size_t)l * E * 4, a_sd,
                                                  h16c, Wt, bpb, conv_bias + l * 64,
                                                  h16n, bnpart, N);
        nbPart = nT64;
        cur ^= 1;
    }

    pool_fc_kernel<<<(G + 3) / 4, 256, 0, stream>>>(h16buf[cur], gptr, fc1_w, fc1_b, fc2_w, fc2_b,
                                                    out, G);
}

// Round 14
// 495.069 us; speedup vs baseline: 1.2797x; 1.0094x over previous
//
#include <hip/hip_runtime.h>
#include <cmath>

#define EPS_BN 1e-5f
#define EPS_SM 1e-16f

typedef _Float16 f16x8 __attribute__((ext_vector_type(8)));
typedef _Float16 f16x4 __attribute__((ext_vector_type(4)));
typedef _Float16 h2 __attribute__((ext_vector_type(2)));
typedef float f32x4 __attribute__((ext_vector_type(4)));
typedef int int2a __attribute__((ext_vector_type(2), aligned(4)));
union F4 { float4 v; float a[4]; };

// ============================ CSR build ============================
__global__ void hist_kernel(const int* __restrict__ edst, int* __restrict__ deg, int E) {
    int e = blockIdx.x * 256 + threadIdx.x;
    if (e < E) atomicAdd(&deg[edst[e]], 1);
}

__global__ void scan1_kernel(const int* __restrict__ deg, int* __restrict__ row_ptr,
                             int* __restrict__ bsum, int N) {
    __shared__ int s[256];
    int t = threadIdx.x;
    int i = blockIdx.x * 256 + t;
    int v = (i < N) ? deg[i] : 0;
    s[t] = v; __syncthreads();
    for (int off = 1; off < 256; off <<= 1) {
        int x = (t >= off) ? s[t - off] : 0;
        __syncthreads();
        s[t] += x;
        __syncthreads();
    }
    if (i < N) row_ptr[i] = s[t] - v;   // exclusive partial
    if (t == 255) bsum[blockIdx.x] = s[t];
}

__global__ void scan2_kernel(int* __restrict__ bsum, int nb) {
    __shared__ int s[1024];
    int t = threadIdx.x;
    int v = (t < nb) ? bsum[t] : 0;
    s[t] = v; __syncthreads();
    for (int off = 1; off < 1024; off <<= 1) {
        int x = (t >= off) ? s[t - off] : 0;
        __syncthreads();
        s[t] += x;
        __syncthreads();
    }
    if (t < nb) bsum[t] = s[t] - v;     // exclusive
}

__global__ void scan3_kernel(int* __restrict__ row_ptr, int* __restrict__ cursor,
                             const int* __restrict__ bsum, int N, int E) {
    int i = blockIdx.x * 256 + threadIdx.x;
    if (i < N) {
        int v = row_ptr[i] + bsum[blockIdx.x];
        row_ptr[i] = v;
        cursor[i] = v;
    } else if (i == N) {
        row_ptr[N] = E;
    }
}

// ============================ merged setup: zero deg | Qm3 | gptr ============================
__global__ void setup_kernel(int* __restrict__ deg, int N, int nb1,
                             const float* __restrict__ convwe, const float* __restrict__ atte,
                             float* __restrict__ Qm3,
                             const int* __restrict__ batch, int* __restrict__ gptr, int G) {
    int b = blockIdx.x;
    int t = threadIdx.x;
    if (b < nb1) {
        int i = b * 256 + t;
        if (i < N) deg[i] = 0;
    } else if (b == nb1) {
        if (t >= 96) return;
        int l = t >> 5, f = (t >> 2) & 7, hh = t & 3;
        const float* we = convwe + (size_t)l * 8 * 256;
        const float* av = atte + (size_t)l * 256;
        float acc = 0.f;
        for (int c = 0; c < 64; c++) acc += we[f * 256 + hh * 64 + c] * av[hh * 64 + c];
        Qm3[t] = acc;
    } else {
        int g = (b - nb1 - 1) * 256 + t;
        if (g > G) return;
        int lo = 0, hi = N;
        while (lo < hi) { int mid = (lo + hi) >> 1; if (batch[mid] < g) lo = mid + 1; else hi = mid; }
        gptr[g] = lo;
    }
}

// scatter edges to CSR order: src_csr[p] = src, ae_csr[l][p][4] = f16(edge_attr@Qm3[l])
__global__ void scatter_kernel(const int* __restrict__ esrc, const int* __restrict__ edst,
                               const float* __restrict__ edge_attr, const float* __restrict__ Qm3,
                               int* __restrict__ cursor, int* __restrict__ src_csr,
                               _Float16* __restrict__ ae_csr, int E) {
    __shared__ float q[96];
    int t = threadIdx.x;
    if (t < 96) q[t] = Qm3[t];
    __syncthreads();
    int e = blockIdx.x * 256 + t;
    if (e >= E) return;
    int src = esrc[e];
    int p = atomicAdd(&cursor[edst[e]], 1);
    src_csr[p] = src;
    F4 ea0, ea1;
    ea0.v = ((const float4*)edge_attr)[(size_t)e * 2];
    ea1.v = ((const float4*)edge_attr)[(size_t)e * 2 + 1];
#pragma unroll
    for (int l = 0; l < 3; l++) {
        const float* ql = q + l * 32;
        f16x4 r;
#pragma unroll
        for (int hh = 0; hh < 4; hh++) {
            float acc = ea0.a[0] * ql[0 * 4 + hh] + ea0.a[1] * ql[1 * 4 + hh]
                      + ea0.a[2] * ql[2 * 4 + hh] + ea0.a[3] * ql[3 * 4 + hh]
                      + ea1.a[0] * ql[4 * 4 + hh] + ea1.a[1] * ql[5 * 4 + hh]
                      + ea1.a[2] * ql[6 * 4 + hh] + ea1.a[3] * ql[7 * 4 + hh];
            r[hh] = (_Float16)acc;
        }
        *(f16x4*)(ae_csr + ((size_t)l * E + p) * 4) = r;
    }
}

// ============================ input projection (h16 + BN partials) ============================
__global__ void proj_kernel(const float* __restrict__ x, const float* __restrict__ lin_w,
                            const float* __restrict__ lin_b,
                            _Float16* __restrict__ h16, float* __restrict__ bnpart, int N) {
    __shared__ float Xs[64 * 32];
    __shared__ float ls[256], lq[256];
    int t = threadIdx.x;
    int col = t & 63, sub = t >> 6;
    float w[32];
#pragma unroll
    for (int k = 0; k < 32; k++) w[k] = lin_w[k * 64 + col];
    float b = lin_b[col];
    int r0 = blockIdx.x * 64;
    const float4* xg = (const float4*)(x + (size_t)r0 * 32);
    float4* Xs4 = (float4*)Xs;
    size_t totf4 = (size_t)N * 8;
#pragma unroll
    for (int i = 0; i < 2; i++) {
        int idx = t + i * 256;
        size_t gidx = (size_t)r0 * 8 + idx;
        Xs4[idx] = (gidx < totf4) ? xg[idx] : make_float4(0.f, 0.f, 0.f, 0.f);
    }
    __syncthreads();
    float ps = 0.f, pq = 0.f;
    for (int rr = sub; rr < 64; rr += 4) {
        int r = r0 + rr;
        if (r >= N) break;
        float acc = b;
        const float4* a4p = (const float4*)(Xs + rr * 32);
#pragma unroll
        for (int kk = 0; kk < 8; kk++) {
            float4 a4 = a4p[kk];
            acc += a4.x * w[kk * 4] + a4.y * w[kk * 4 + 1] + a4.z * w[kk * 4 + 2] + a4.w * w[kk * 4 + 3];
        }
        float hv = fmaxf(acc, 0.f);
        h16[(size_t)r * 64 + col] = (_Float16)hv;
        ps += hv; pq += hv * hv;
    }
    ls[t] = ps; lq[t] = pq;
    __syncthreads();
    if (t < 64) {
        bnpart[(size_t)blockIdx.x * 128 + t] = ls[t] + ls[t + 64] + ls[t + 128] + ls[t + 192];
        bnpart[(size_t)blockIdx.x * 128 + 64 + t] = lq[t] + lq[t + 64] + lq[t + 128] + lq[t + 192];
    }
}

// reduce bnpart over blocks: red[stat] = sum_b bnpart[b][stat], stat = blockIdx (128 blocks)
__global__ void bn_reduce_kernel(const float* __restrict__ bnpart, int nb, float* __restrict__ red) {
    __shared__ float s[256];
    int stat = blockIdx.x;
    float acc = 0.f;
    for (int j = threadIdx.x; j < nb; j += 256) acc += bnpart[(size_t)j * 128 + stat];
    s[threadIdx.x] = acc;
    __syncthreads();
    for (int off = 128; off >= 1; off >>= 1) {
        if (threadIdx.x < off) s[threadIdx.x] += s[threadIdx.x + off];
        __syncthreads();
    }
    if (threadIdx.x == 0) red[stat] = s[0];
}

// ============================ fold (parallel) ============================
// blocks 0..63 : Wt[col=b][k=t] = 0.25*scl[k>>2]*convw[(k>>2)*256 + (k&3)*64 + col]
// block 64     : Pt[o][k] f16 = scl[k]*dot(convw[k][hh*64..], att{s|d}[hh]); rows 8..15 = 0
// block 65     : bpb[t] = sum_k sft[k]*convw[k][t];  then cs[8]
__global__ void fold2_kernel(const float* __restrict__ red,
                             const float* __restrict__ gamma, const float* __restrict__ beta,
                             const float* __restrict__ convw,
                             const float* __restrict__ atts, const float* __restrict__ attd,
                             _Float16* __restrict__ Wt, float* __restrict__ bpb,
                             _Float16* __restrict__ Pt, float* __restrict__ cs,
                             float invN) {
    __shared__ float scl[64], sft[64], bs[256];
    int t = threadIdx.x;
    if (t < 64) {
        float mu = red[t] * invN;
        float var = fmaxf(red[64 + t] * invN - mu * mu, 0.f);
        float sc = gamma[t] / sqrtf(var + EPS_BN);
        scl[t] = sc;
        sft[t] = beta[t] - mu * sc;
    }
    __syncthreads();
    int b = blockIdx.x;
    if (b < 64) {
        int col = b;
        int c = t >> 2, hh = t & 3;
        Wt[col * 256 + t] = (_Float16)(0.25f * scl[c] * convw[c * 256 + hh * 64 + col]);
    } else if (b == 64) {
        for (int idx = t; idx < 512; idx += 256) {
            int k = idx >> 3, o = idx & 7, hh = o & 3;
            const float* av = (o < 4) ? atts : attd;
            float acc = 0.f;
            for (int c2 = 0; c2 < 64; c2++) acc += convw[k * 256 + hh * 64 + c2] * av[hh * 64 + c2];
            Pt[o * 64 + k] = (_Float16)(scl[k] * acc);
        }
        for (int idx = t; idx < 512; idx += 256) Pt[512 + idx] = (_Float16)0.f;
    } else {
        float bacc = 0.f;
        for (int k = 0; k < 64; k++) bacc += sft[k] * convw[k * 256 + t];
        bpb[t] = bacc;
        bs[t] = bacc;
        __syncthreads();
        if (t < 8) {
            int hh = t & 3;
            const float* av = (t < 4) ? atts : attd;
            float acc = 0.f;
            for (int c2 = 0; c2 < 64; c2++) acc += bs[hh * 64 + c2] * av[hh * 64 + c2];
            cs[t] = acc;
        }
    }
}

// ============================ per-node attention logits via MFMA ============================
// a_sd[64x8 per block] = h16[64x64] @ Pt^T  (+cs). 4 waves x 16 rows; two 16x16x32 MFMAs
// per wave (K=64). A loaded directly from h16 in fragment layout; B from Pt[16][64] f16.
__global__ __launch_bounds__(256) void att_node_kernel(
        const _Float16* __restrict__ h16, const _Float16* __restrict__ Pt,
        const float* __restrict__ cs, _Float16* __restrict__ a_sd, int N) {
    int t = threadIdx.x;
    int wv = t >> 6, lane = t & 63;
    int m = lane & 15, quad = lane >> 4, kb = quad * 8;
    int r0 = blockIdx.x * 64 + wv * 16;
    f16x8 b0 = *(const f16x8*)(Pt + m * 64 + kb);
    f16x8 b1 = *(const f16x8*)(Pt + m * 64 + 32 + kb);
    f16x8 a0 = {}, a1 = {};
    int rm = r0 + m;
    if (rm < N) {
        a0 = *(const f16x8*)(h16 + ((size_t)rm << 6) + kb);
        a1 = *(const f16x8*)(h16 + ((size_t)rm << 6) + 32 + kb);
    }
    f32x4 acc = {0.f, 0.f, 0.f, 0.f};
    acc = __builtin_amdgcn_mfma_f32_16x16x32_f16(a0, b0, acc, 0, 0, 0);
    acc = __builtin_amdgcn_mfma_f32_16x16x32_f16(a1, b1, acc, 0, 0, 0);
    if (m < 8) {
        float cso = cs[m];
#pragma unroll
        for (int reg = 0; reg < 4; reg++) {
            int rg = r0 + quad * 4 + reg;
            if (rg < N) a_sd[(size_t)rg * 8 + m] = (_Float16)(acc[reg] + cso);
        }
    }
}

// ============================ fused scores + aggregation + projection (MFMA) ============================
// 32-node tile per block, 4 waves; slot = 16 lanes owns TWO nodes (rows wv*8+slot, +4),
// edge chunks interleaved -> 4 independent gather chains/wave-slot-pair. 2-edge chunks:
// one int2 src load, 2 independent 8B f16 h-row gathers, scoring on lanes j<2, 8 shuffles,
// 16 pk_fma (fp16 packed, channel-major). MFMA projects two 16-row tiles.
__global__ __launch_bounds__(256) void msg_proj_kernel(
        const int* __restrict__ row_ptr, const int* __restrict__ src_csr,
        const _Float16* __restrict__ ae_l, const _Float16* __restrict__ a_sd,
        const _Float16* __restrict__ h16_in,
        const _Float16* __restrict__ Wt, const float* __restrict__ bpb,
        const float* __restrict__ bias,
        _Float16* __restrict__ h16_out, float* __restrict__ bnpart, int N) {
    __shared__ __attribute__((aligned(16))) _Float16 Aagg[32][264];
    __shared__ __attribute__((aligned(16))) float sals[32][4];
    int t = threadIdx.x;
    int wv = t >> 6, lane = t & 63;
    int colg = wv * 16 + (lane & 15);
    int kb = (lane >> 4) * 8;
    int slot = lane >> 4, c4 = lane & 15;
    int head = c4 & 3, j = c4 >> 2;
    int sb_ = lane & 48;   // slot base lane in wave
    int nb0 = blockIdx.x * 32;
    int rows[2] = {wv * 8 + slot, wv * 8 + slot + 4};

    float bpbc[4];
#pragma unroll
    for (int hh = 0; hh < 4; hh++) bpbc[hh] = bpb[hh * 64 + colg] * 0.25f;
    float bcol = bias[colg];

    h2 Acc[2][4][2];    // [node][head][channel-pair], fp16 packed
    float dd[2][4];
    int p1v[2];
    float adv[2];
    int base0, base1;
#pragma unroll
    for (int u = 0; u < 2; u++) {
#pragma unroll
        for (int h = 0; h < 4; h++) {
            Acc[u][h][0] = (h2){(_Float16)0.f, (_Float16)0.f};
            Acc[u][h][1] = (h2){(_Float16)0.f, (_Float16)0.f};
            dd[u][h] = 0.f;
        }
        int n = nb0 + rows[u];
        int p0 = 0, p1 = 0;
        if (n < N) { p0 = row_ptr[n]; p1 = row_ptr[n + 1]; }
        adv[u] = (p0 < p1) ? (float)a_sd[(size_t)n * 8 + 4 + head] : 0.f;
        p1v[u] = p1;
        if (u == 0) base0 = p0; else base1 = p0;
    }

    auto chunk = [&](int u, int base) {
        int rem = p1v[u] - base;
        int2a sv = *(const int2a*)(src_csr + base);
        int sa = sv.x;
        int sbv = rem > 1 ? sv.y : sa;
        int mysrc = (j == 1) ? sbv : sa;
        float myas = (float)a_sd[(size_t)mysrc * 8 + head];
        int jc = (j == 1 && rem > 1) ? 1 : 0;
        float aev = (float)ae_l[(size_t)(base + jc) * 4 + head];
        union H4 { f16x4 v; h2 p[2]; } ua, ub;
        ua.v = *(const f16x4*)(h16_in + ((size_t)sa << 6) + (c4 << 2));
        ub.v = *(const f16x4*)(h16_in + ((size_t)sbv << 6) + (c4 << 2));
        float s = myas + adv[u] + aev;
        s = s > 0.f ? s : 0.2f * s;
        float ex = (j < 2 && j < rem) ? __expf(s) : 0.f;
        float ea0 = __shfl(ex, sb_ + 0), ea1 = __shfl(ex, sb_ + 1);
        float ea2 = __shfl(ex, sb_ + 2), ea3 = __shfl(ex, sb_ + 3);
        float eb0 = __shfl(ex, sb_ + 4), eb1 = __shfl(ex, sb_ + 5);
        float eb2 = __shfl(ex, sb_ + 6), eb3 = __shfl(ex, sb_ + 7);
        dd[u][0] += ea0 + eb0;
        dd[u][1] += ea1 + eb1;
        dd[u][2] += ea2 + eb2;
        dd[u][3] += ea3 + eb3;
#define ACC_ROW(HU, E0, E1, E2, E3)                                           \
        {                                                                     \
            _Float16 w0 = (_Float16)(E0), w1 = (_Float16)(E1);                \
            _Float16 w2 = (_Float16)(E2), w3 = (_Float16)(E3);                \
            h2 W0 = {w0, w0}, W1 = {w1, w1}, W2 = {w2, w2}, W3 = {w3, w3};    \
            Acc[u][0][0] += W0 * HU.p[0]; Acc[u][0][1] += W0 * HU.p[1];       \
            Acc[u][1][0] += W1 * HU.p[0]; Acc[u][1][1] += W1 * HU.p[1];       \
            Acc[u][2][0] += W2 * HU.p[0]; Acc[u][2][1] += W2 * HU.p[1];       \
            Acc[u][3][0] += W3 * HU.p[0]; Acc[u][3][1] += W3 * HU.p[1];       \
        }
        ACC_ROW(ua, ea0, ea1, ea2, ea3)
        ACC_ROW(ub, eb0, eb1, eb2, eb3)
#undef ACC_ROW
    };

    while (base0 < p1v[0] || base1 < p1v[1]) {
        if (base0 < p1v[0]) chunk(0, base0);
        if (base1 < p1v[1]) chunk(1, base1);
        base0 += 2; base1 += 2;
    }

#pragma unroll
    for (int u = 0; u < 2; u++) {
        f16x8 v0, v1;
#pragma unroll
        for (int h = 0; h < 4; h++) {
            float d = dd[u][h];
            float invd = d > 0.f ? 1.f / (d + EPS_SM) : 0.f;
            _Float16 ih = (_Float16)invd;
            h2 IH = {ih, ih};
            h2 q0 = Acc[u][h][0] * IH;
            h2 q1 = Acc[u][h][1] * IH;
            v0[h] = q0.x; v0[4 + h] = q0.y;
            v1[h] = q1.x; v1[4 + h] = q1.y;
        }
        *(f16x8*)&Aagg[rows[u]][c4 * 16] = v0;
        *(f16x8*)&Aagg[rows[u]][c4 * 16 + 8] = v1;
        if (c4 == 0) {
            float4 sv2;
            sv2.x = dd[u][0] / (dd[u][0] + EPS_SM);
            sv2.y = dd[u][1] / (dd[u][1] + EPS_SM);
            sv2.z = dd[u][2] / (dd[u][2] + EPS_SM);
            sv2.w = dd[u][3] / (dd[u][3] + EPS_SM);
            *(float4*)&sals[rows[u]][0] = sv2;
        }
    }
    // B fragments loaded here (overlaps LDS drain before the barrier)
    f16x8 bfrag[8];
    const _Float16* wtp = Wt + (size_t)colg * 256 + kb;
#pragma unroll
    for (int ks = 0; ks < 8; ks++) bfrag[ks] = *(const f16x8*)(wtp + ks * 32);
    __syncthreads();

    // -------- MFMA phase: two 16-row tiles --------
    float ps = 0.f, pq = 0.f;
#pragma unroll
    for (int half = 0; half < 2; half++) {
        f32x4 acc = {0.f, 0.f, 0.f, 0.f};
        const _Float16* ap = &Aagg[half * 16 + (lane & 15)][kb];
#pragma unroll
        for (int ks = 0; ks < 8; ks++) {
            f16x8 af = *(const f16x8*)(ap + ks * 32);
            acc = __builtin_amdgcn_mfma_f32_16x16x32_f16(af, bfrag[ks], acc, 0, 0, 0);
        }
        int r0 = half * 16 + (lane >> 4) * 4;
#pragma unroll
        for (int reg = 0; reg < 4; reg++) {
            int rr = r0 + reg;
            int nn = nb0 + rr;
            if (nn < N) {
                float v = acc[reg] + sals[rr][0] * bpbc[0] + sals[rr][1] * bpbc[1]
                        + sals[rr][2] * bpbc[2] + sals[rr][3] * bpbc[3] + bcol;
                size_t idx = ((size_t)nn << 6) + colg;
                float hv = (float)h16_in[idx];
                float outv = fmaxf(v, 0.f) + hv;
                h16_out[idx] = (_Float16)outv;
                ps += outv;
                pq += outv * outv;
            }
        }
    }
    // reduce the 4 row-quads (lanes differing in bits 4,5) -> per-col BN partials
    ps += __shfl_xor(ps, 16); ps += __shfl_xor(ps, 32);
    pq += __shfl_xor(pq, 16); pq += __shfl_xor(pq, 32);
    if ((lane >> 4) == 0) {
        bnpart[(size_t)blockIdx.x * 128 + colg] = ps;
        bnpart[(size_t)blockIdx.x * 128 + 64 + colg] = pq;
    }
}

// ============================ pooling + FC head ============================
__global__ void pool_fc_kernel(const _Float16* __restrict__ h16, const int* __restrict__ gptr,
                               const float* __restrict__ fc1_w, const float* __restrict__ fc1_b,
                               const float* __restrict__ fc2_w, const float* __restrict__ fc2_b,
                               float* __restrict__ out, int G) {
    __shared__ float pool[4][64];
    int lane = threadIdx.x & 63, wv = threadIdx.x >> 6;
    int g = blockIdx.x * 4 + wv;
    float acc = 0.f;
    if (g < G) {
        int a = gptr[g], b = gptr[g + 1];
        for (int r = a; r < b; r++) acc += (float)h16[(size_t)r * 64 + lane];
    }
    pool[wv][lane] = acc;
    __syncthreads();
    float z1 = fc1_b[lane];
#pragma unroll 8
    for (int c = 0; c < 64; c++) z1 += pool[wv][c] * fc1_w[c * 64 + lane];
    z1 = fmaxf(z1, 0.f);
    float z2 = z1 * fc2_w[lane];
    z2 += __shfl_xor(z2, 1);
    z2 += __shfl_xor(z2, 2);
    z2 += __shfl_xor(z2, 4);
    z2 += __shfl_xor(z2, 8);
    z2 += __shfl_xor(z2, 16);
    z2 += __shfl_xor(z2, 32);
    if (g < G && lane == 0) out[g] = fmaxf(z2 + fc2_b[0], 0.f);
}

// ============================ host ============================
extern "C" void kernel_launch(void* const* d_in, const int* in_sizes, int n_in,
                              void* d_out, int out_size, void* d_ws, size_t ws_size,
                              hipStream_t stream) {
    const float* x         = (const float*)d_in[0];
    const int*   eindex    = (const int*)d_in[1];
    const float* edge_attr = (const float*)d_in[2];
    const int*   batch     = (const int*)d_in[3];
    const float* lin_w     = (const float*)d_in[4];
    const float* lin_b     = (const float*)d_in[5];
    const float* bn_gamma  = (const float*)d_in[6];
    const float* bn_beta   = (const float*)d_in[7];
    const float* conv_w    = (const float*)d_in[8];
    const float* conv_we   = (const float*)d_in[9];
    const float* att_src   = (const float*)d_in[10];
    const float* att_dst   = (const float*)d_in[11];
    const float* att_edge  = (const float*)d_in[12];
    const float* conv_bias = (const float*)d_in[13];
    const float* fc1_w     = (const float*)d_in[14];
    const float* fc1_b     = (const float*)d_in[15];
    const float* fc2_w     = (const float*)d_in[16];
    const float* fc2_b     = (const float*)d_in[17];
    float* out = (float*)d_out;

    int N = in_sizes[3];
    int E = in_sizes[1] / 2;
    int G = out_size;
    const int* esrc = eindex;
    const int* edst = eindex + E;

    char* wp = (char*)d_ws;
    auto carve = [&](size_t b) -> char* {
        char* p = wp;
        wp += (b + 511) & ~(size_t)511;
        return p;
    };
    _Float16*  h16b0  = (_Float16*)carve((size_t)N * 64 * 2);     // 25.6 MB
    _Float16*  h16b1  = (_Float16*)carve((size_t)N * 64 * 2);     // 25.6 MB
    _Float16*  a_sd   = (_Float16*)carve((size_t)N * 8 * 2);      //  3.2 MB
    _Float16*  ae_csr = (_Float16*)carve((size_t)3 * E * 4 * 2);  //  9.6 MB
    int*       src_csr= (int*)carve((size_t)(E + 4) * 4);         //  1.6 MB (+pad for tail)
    int*       deg    = (int*)carve((size_t)N * 4);
    int*       row_ptr= (int*)carve((size_t)(N + 1) * 4);
    int*       cursor = (int*)carve((size_t)N * 4);
    int*       bsum   = (int*)carve(4096);
    int*       gptr   = (int*)carve((size_t)(G + 1) * 4);
    float*     bpb    = (float*)carve(256 * 4);
    _Float16*  Pt     = (_Float16*)carve(1024 * 2);
    float*     cs     = (float*)carve(8 * 4);
    float*     Qm3    = (float*)carve(96 * 4);
    _Float16*  Wt     = (_Float16*)carve(64 * 256 * 2);
    float*     red    = (float*)carve(128 * 4);
    int nb1 = (N + 255) / 256;
    int nbP = (N + 63) / 64;
    int nTiles = (N + 31) / 32;
    int maxPart = nbP > nTiles ? nbP : nTiles;
    float*     bnpart = (float*)carve((size_t)maxPart * 128 * 4);

    // merged setup (zero deg | Qm3 | gptr), then CSR + scatter
    int gBlocks = (G + 1 + 255) / 256;
    setup_kernel<<<nb1 + 1 + gBlocks, 256, 0, stream>>>(deg, N, nb1, conv_we, att_edge, Qm3,
                                                        batch, gptr, G);
    hist_kernel<<<(E + 255) / 256, 256, 0, stream>>>(edst, deg, E);
    scan1_kernel<<<nb1, 256, 0, stream>>>(deg, row_ptr, bsum, N);
    scan2_kernel<<<1, 1024, 0, stream>>>(bsum, nb1);
    scan3_kernel<<<(N + 1 + 255) / 256, 256, 0, stream>>>(row_ptr, cursor, bsum, N, E);
    scatter_kernel<<<(E + 255) / 256, 256, 0, stream>>>(esrc, edst, edge_attr, Qm3,
                                                        cursor, src_csr, ae_csr, E);

    // input projection (+ BN partials for layer 0)
    proj_kernel<<<nbP, 256, 0, stream>>>(x, lin_w, lin_b, h16b0, bnpart, N);

    int cur = 0;
    _Float16* h16buf[2] = {h16b0, h16b1};
    int nbPart = nbP;   // partial count for current layer's BN

    for (int l = 0; l < 3; l++) {
        _Float16* h16c = h16buf[cur];
        _Float16* h16n = h16buf[cur ^ 1];
        bn_reduce_kernel<<<128, 256, 0, stream>>>(bnpart, nbPart, red);
        fold2_kernel<<<66, 256, 0, stream>>>(red,
                                             bn_gamma + l * 64, bn_beta + l * 64,
                                             conv_w + (size_t)l * 64 * 256,
                                             att_src + l * 256, att_dst + l * 256,
                                             Wt, bpb, Pt, cs, 1.f / (float)N);
        att_node_kernel<<<(N + 63) / 64, 256, 0, stream>>>(h16c, Pt, cs, a_sd, N);
        msg_proj_kernel<<<nTiles, 256, 0, stream>>>(row_ptr, src_csr,
                                                    ae_csr + (size_t)l * E * 4, a_sd,
                                                    h16c, Wt, bpb, conv_bias + l * 64,
                                                    h16n, bnpart, N);
        nbPart = nTiles;
        cur ^= 1;
    }

    pool_fc_kernel<<<(G + 3) / 4, 256, 0, stream>>>(h16buf[cur], gptr, fc1_w, fc1_b, fc2_w, fc2_b,
                                                    out, G);
}